// Round 1
// baseline (723.034 us; speedup 1.0000x reference)
//
#include <hip/hip_runtime.h>

#define B_   8
#define C_   64
#define W_   128
#define H_   128
#define K_   9
#define OUT_ 64
#define NPIX (B_*W_*H_)      // 131072
#define EPS_ 1e-5f

// ---------------- workspace layout (floats) ----------------
#define FEAT_OFF    0                      // B*W*H*C  = 8388608  (NHWC f)
#define OFFPRE_OFF  8388608                // B*9*W*H  = 1179648
#define XPRE_OFF    9568256                // B*64*W*H = 8388608
#define WT_OFF      17956864               // 9*64*64  = 36864   (w_dsc as [k][c][o])
#define BNSTATS_OFF 17993728               // 18  (sum,sumsq per ck)
#define BNAB_OFF    17993746               // 18  (A,B per ck)
#define GSTATS_OFF  17993764               // 256 (sum,sumsq per (b,g))
#define GNFIN_OFF   17994020               // 256 (mean,istd per (b,g))
#define STATS_BYTES ((18+18+256+256)*sizeof(float))

// ---------------- NCHW -> NHWC transpose of f ----------------
__global__ __launch_bounds__(256) void k_nhwc(const float* __restrict__ f,
                                              float* __restrict__ feat) {
    __shared__ float tile[64][65];
    int bid = blockIdx.x;
    int ht = bid & 1;            // 64-high h tile
    int w  = (bid >> 1) & 127;
    int b  = bid >> 8;
    int t  = threadIdx.x;
    int lh = t & 63;
    int c0 = (t >> 6) * 16;
    const float* fp = f + (((b*64)*128 + w)*128) + ht*64 + lh;
#pragma unroll
    for (int i = 0; i < 16; i++) {
        int c = c0 + i;
        tile[c][lh] = fp[c*16384];
    }
    __syncthreads();
    int lc = t & 63;
    int h0 = (t >> 6) * 16;
    float* op = feat + (((b*128 + w)*128) + ht*64)*64 + lc;
#pragma unroll
    for (int i = 0; i < 16; i++) {
        int hr = h0 + i;
        op[hr*64] = tile[lc][hr];
    }
}

// ---------------- w_dsc (O,C,K) -> wT[k][c][o] ----------------
__global__ void k_wt(const float* __restrict__ w_dsc, float* __restrict__ wT) {
    int i = blockIdx.x*256 + threadIdx.x;       // < 36864
    if (i >= 9*64*64) return;
    int o = i & 63;
    int c = (i >> 6) & 63;
    int k = i >> 12;
    wT[i] = w_dsc[(o*64 + c)*9 + k];
}

// ---------------- 3x3 conv (9 out channels) + BN stats ----------------
__global__ __launch_bounds__(256) void k_conv_off(const float* __restrict__ f,
                                                  const float* __restrict__ w_off,
                                                  const float* __restrict__ b_off,
                                                  float* __restrict__ off_pre,
                                                  float* __restrict__ bnstats) {
    __shared__ float wsh[64][9][16];   // [c][tap][ck] (pad 16 for alignment)
    int t = threadIdx.x;
    for (int i = t; i < 9*576; i += 256) {
        int ck = i / 576; int r = i % 576; int c = r / 9; int tap = r % 9;
        wsh[c][tap][ck] = w_off[i];    // w_off flat: ck*576 + c*9 + tap
    }
    __syncthreads();

    int p = blockIdx.x*256 + t;
    int b = p >> 14; int w = (p >> 7) & 127; int h = p & 127;
    float acc[9];
#pragma unroll
    for (int ck = 0; ck < 9; ck++) acc[ck] = b_off[ck];

    const float* fb = f + ((size_t)(b*64)*128)*128;
    for (int dw = -1; dw <= 1; dw++) {
        int wy = w + dw; if ((unsigned)wy >= 128u) continue;
        for (int dh = -1; dh <= 1; dh++) {
            int hx = h + dh; if ((unsigned)hx >= 128u) continue;
            int tap = (dw+1)*3 + (dh+1);
            const float* fp = fb + wy*128 + hx;
            for (int c = 0; c < 64; c++) {
                float v = fp[c*16384];
#pragma unroll
                for (int ck = 0; ck < 9; ck++) acc[ck] += v * wsh[c][tap][ck];
            }
        }
    }
#pragma unroll
    for (int ck = 0; ck < 9; ck++)
        off_pre[((b*9+ck) << 14) + (w << 7) + h] = acc[ck];

    // per-channel wave reduction -> global atomics
    int lane = t & 63;
#pragma unroll
    for (int ck = 0; ck < 9; ck++) {
        float v1 = acc[ck], v2 = acc[ck]*acc[ck];
        for (int off = 32; off; off >>= 1) {
            v1 += __shfl_down(v1, off);
            v2 += __shfl_down(v2, off);
        }
        if (lane == 0) {
            atomicAdd(&bnstats[ck*2],   v1);
            atomicAdd(&bnstats[ck*2+1], v2);
        }
    }
}

// ---------------- BN finalize ----------------
__global__ void k_bn_fin(const float* __restrict__ bnstats,
                         const float* __restrict__ bn_gamma,
                         const float* __restrict__ bn_beta,
                         float* __restrict__ bnAB) {
    int t = threadIdx.x;
    if (t < 9) {
        float n    = (float)NPIX;
        float mean = bnstats[t*2] / n;
        float var  = bnstats[t*2+1] / n - mean*mean;
        float A    = bn_gamma[t] / sqrtf(var + EPS_);
        bnAB[t*2]   = A;
        bnAB[t*2+1] = bn_beta[t] - mean * A;
    }
}

// ---------------- fused: BN+tanh+cumsum offsets, bilinear sample, strip conv, GN stats ----------------
__global__ __launch_bounds__(256) void k_sample_dsc(const float* __restrict__ feat,
                                                    const float* __restrict__ off_pre,
                                                    const float* __restrict__ bnAB,
                                                    const float* __restrict__ wT,
                                                    const float* __restrict__ b_dsc,
                                                    float* __restrict__ xpre,
                                                    float* __restrict__ gstats) {
    __shared__ float ynew[9][128];
    __shared__ float wk[64][68];     // [c][o]
    __shared__ float samp[128][68];  // [h][c]
    __shared__ float red[16][2];

    int t = threadIdx.x;
    int bid = blockIdx.x;
    int b = bid >> 7; int w = bid & 127;

    if (t < 128) {
        int h = t;
        float y[9];
#pragma unroll
        for (int ck = 0; ck < 9; ck++) {
            float v = off_pre[((b*9+ck) << 14) + (w << 7) + h];
            y[ck] = tanhf(bnAB[ck*2]*v + bnAB[ck*2+1]);
        }
        float ofn[9];
        ofn[4] = 0.f;
        ofn[5] = y[5]; ofn[6] = y[5]+y[6]; ofn[7] = y[5]+y[6]+y[7];
        ofn[3] = y[3]; ofn[2] = y[3]+y[2]; ofn[1] = y[3]+y[2]+y[1];
        ofn[0] = y[0]; ofn[8] = y[8];
#pragma unroll
        for (int k = 0; k < 9; k++) ynew[k][h] = (float)w + ofn[k];
    }
    if (t < 16) { red[t][0] = 0.f; red[t][1] = 0.f; }

    float acc[4][8];
#pragma unroll
    for (int i = 0; i < 4; i++)
#pragma unroll
        for (int j = 0; j < 8; j++) acc[i][j] = 0.f;

    int og = (t & 15) * 4;   // 4 output channels (one GN group)
    int q  = t >> 4;         // 16 h-slices
    int h0 = q * 8;

    __syncthreads();

    for (int k = 0; k < 9; k++) {
        // stage weight slice [c][o]
        const float* wkg = wT + k*4096;
        for (int i = t; i < 4096; i += 256)
            wk[i >> 6][i & 63] = wkg[i];

        // stage bilinear samples for this k: thread -> (h, half-of-c)
        {
            int h  = t >> 1;
            int cb = (t & 1) * 32;
            float ys = ynew[k][h];
            float xs = (float)(k - 4 + h);
            int y0 = (int)floorf(ys);
            int x0 = k - 4 + h;
            int y0c = min(max(y0, 0), 127), y1c = min(max(y0+1, 0), 127);
            int x0c = min(max(x0, 0), 127), x1c = min(max(x0+1, 0), 127);
            float wa = ((float)y1c - ys) * ((float)x1c - xs);
            float wb = ((float)y1c - ys) * (xs - (float)x0c);
            float wc = (ys - (float)y0c) * ((float)x1c - xs);
            float wd = (ys - (float)y0c) * (xs - (float)x0c);
            const float* pb  = feat + ((size_t)b << 20);
            const float* p00 = pb + (y0c*128 + x0c)*64 + cb;
            const float* p01 = pb + (y0c*128 + x1c)*64 + cb;
            const float* p10 = pb + (y1c*128 + x0c)*64 + cb;
            const float* p11 = pb + (y1c*128 + x1c)*64 + cb;
#pragma unroll
            for (int cc = 0; cc < 32; cc += 4) {
                float4 a  = *(const float4*)(p00+cc);
                float4 b4 = *(const float4*)(p01+cc);
                float4 c4 = *(const float4*)(p10+cc);
                float4 d4 = *(const float4*)(p11+cc);
                float4 r;
                r.x = a.x*wa + b4.x*wb + c4.x*wc + d4.x*wd;
                r.y = a.y*wa + b4.y*wb + c4.y*wc + d4.y*wd;
                r.z = a.z*wa + b4.z*wb + c4.z*wc + d4.z*wd;
                r.w = a.w*wa + b4.w*wb + c4.w*wc + d4.w*wd;
                *(float4*)&samp[h][cb+cc] = r;
            }
        }
        __syncthreads();

        // accumulate: acc[oo][j] += samp[h0+j][c] * wk[c][og+oo]
#pragma unroll 4
        for (int cb = 0; cb < 64; cb += 4) {
            float4 w0 = *(const float4*)&wk[cb+0][og];
            float4 w1 = *(const float4*)&wk[cb+1][og];
            float4 w2 = *(const float4*)&wk[cb+2][og];
            float4 w3 = *(const float4*)&wk[cb+3][og];
#pragma unroll
            for (int j = 0; j < 8; j++) {
                float4 s = *(const float4*)&samp[h0+j][cb];
                acc[0][j] += s.x*w0.x + s.y*w1.x + s.z*w2.x + s.w*w3.x;
                acc[1][j] += s.x*w0.y + s.y*w1.y + s.z*w2.y + s.w*w3.y;
                acc[2][j] += s.x*w0.z + s.y*w1.z + s.z*w2.z + s.w*w3.z;
                acc[3][j] += s.x*w0.w + s.y*w1.w + s.z*w2.w + s.w*w3.w;
            }
        }
        __syncthreads();
    }

    // epilogue: bias, GN partial stats, write xpre
    float s1 = 0.f, s2 = 0.f;
#pragma unroll
    for (int oo = 0; oo < 4; oo++) {
        float bias = b_dsc[og+oo];
#pragma unroll
        for (int j = 0; j < 8; j++) {
            float v = acc[oo][j] + bias;
            acc[oo][j] = v;
            s1 += v; s2 += v*v;
        }
    }
    atomicAdd(&red[t & 15][0], s1);
    atomicAdd(&red[t & 15][1], s2);
#pragma unroll
    for (int oo = 0; oo < 4; oo++) {
        float* xp = xpre + (((b*64 + og + oo)*128 + w) << 7) + h0;
        *(float4*)(xp+0) = make_float4(acc[oo][0], acc[oo][1], acc[oo][2], acc[oo][3]);
        *(float4*)(xp+4) = make_float4(acc[oo][4], acc[oo][5], acc[oo][6], acc[oo][7]);
    }
    __syncthreads();
    if (t < 16) {
        atomicAdd(&gstats[(b*16 + t)*2],   red[t][0]);
        atomicAdd(&gstats[(b*16 + t)*2+1], red[t][1]);
    }
}

// ---------------- GN finalize ----------------
__global__ void k_gn_fin(const float* __restrict__ gstats, float* __restrict__ gnfin) {
    int t = threadIdx.x;
    if (t < 128) {
        float n    = 65536.f;           // 4 ch * 128 * 128
        float mean = gstats[t*2] / n;
        float var  = gstats[t*2+1] / n - mean*mean;
        gnfin[t*2]   = mean;
        gnfin[t*2+1] = 1.0f / sqrtf(var + EPS_);
    }
}

// ---------------- GN apply + ReLU ----------------
__global__ __launch_bounds__(256) void k_gn_apply(const float* __restrict__ xpre,
                                                  const float* __restrict__ gnfin,
                                                  const float* __restrict__ gn_gamma,
                                                  const float* __restrict__ gn_beta,
                                                  float* __restrict__ out) {
    int i4  = blockIdx.x*256 + threadIdx.x;
    int idx = i4 * 4;
    int o = (idx >> 14) & 63;
    int b = idx >> 20;
    int g = o >> 2;
    float mean = gnfin[(b*16+g)*2];
    float istd = gnfin[(b*16+g)*2+1];
    float ga = gn_gamma[o] * istd;
    float be = gn_beta[o] - mean * ga;
    float4 v = *(const float4*)(xpre + idx);
    v.x = fmaxf(v.x*ga + be, 0.f);
    v.y = fmaxf(v.y*ga + be, 0.f);
    v.z = fmaxf(v.z*ga + be, 0.f);
    v.w = fmaxf(v.w*ga + be, 0.f);
    *(float4*)(out + idx) = v;
}

extern "C" void kernel_launch(void* const* d_in, const int* in_sizes, int n_in,
                              void* d_out, int out_size, void* d_ws, size_t ws_size,
                              hipStream_t stream) {
    const float* f        = (const float*)d_in[0];
    const float* w_off    = (const float*)d_in[1];
    const float* b_off    = (const float*)d_in[2];
    const float* bn_gamma = (const float*)d_in[3];
    const float* bn_beta  = (const float*)d_in[4];
    const float* w_dsc    = (const float*)d_in[5];
    const float* b_dsc    = (const float*)d_in[6];
    const float* gn_gamma = (const float*)d_in[7];
    const float* gn_beta  = (const float*)d_in[8];

    float* ws      = (float*)d_ws;
    float* feat    = ws + FEAT_OFF;
    float* off_pre = ws + OFFPRE_OFF;
    float* xpre    = ws + XPRE_OFF;
    float* wT      = ws + WT_OFF;
    float* bnstats = ws + BNSTATS_OFF;
    float* bnAB    = ws + BNAB_OFF;
    float* gstats  = ws + GSTATS_OFF;
    float* gnfin   = ws + GNFIN_OFF;

    hipMemsetAsync(bnstats, 0, STATS_BYTES, stream);

    k_nhwc<<<2048, 256, 0, stream>>>(f, feat);
    k_wt<<<144, 256, 0, stream>>>(w_dsc, wT);
    k_conv_off<<<512, 256, 0, stream>>>(f, w_off, b_off, off_pre, bnstats);
    k_bn_fin<<<1, 32, 0, stream>>>(bnstats, bn_gamma, bn_beta, bnAB);
    k_sample_dsc<<<1024, 256, 0, stream>>>(feat, off_pre, bnAB, wT, b_dsc, xpre, gstats);
    k_gn_fin<<<1, 128, 0, stream>>>(gstats, gnfin);
    k_gn_apply<<<8192, 256, 0, stream>>>(xpre, gnfin, gn_gamma, gn_beta, (float*)d_out);
}

// Round 3
// 413.672 us; speedup vs baseline: 1.7478x; 1.7478x over previous
//
#include <hip/hip_runtime.h>

#define B_   8
#define C_   64
#define W_   128
#define H_   128
#define K_   9
#define OUT_ 64
#define NPIX (B_*W_*H_)      // 131072
#define EPS_ 1e-5f

// ---------------- workspace layout (floats) ----------------
#define FEAT_OFF    0                      // B*W*H*C  = 8388608  (NHWC f)
#define OFFPRE_OFF  8388608                // B*9*W*H  = 1179648
#define XPRE_OFF    9568256                // B*64*W*H = 8388608
#define WT_OFF      17956864               // 9*64*64  = 36864   (w_dsc as [k][c][o])
#define BNSTATS_OFF 17993728               // 18  (sum,sumsq per ck)
#define BNAB_OFF    17993746               // 18  (A,B per ck)
#define GSTATS_OFF  17993764               // 256 (sum,sumsq per (b,g))
#define GNFIN_OFF   17994020               // 256 (mean,istd per (b,g))
#define WP_OFF      17994276               // 3*9*3*64 = 5184 (w_off repacked)
#define STATS_BYTES ((18+18+256+256)*sizeof(float))

// ---------------- NCHW -> NHWC transpose of f ----------------
__global__ __launch_bounds__(256) void k_nhwc(const float* __restrict__ f,
                                              float* __restrict__ feat) {
    __shared__ float tile[64][65];
    int bid = blockIdx.x;
    int ht = bid & 1;            // 64-high h tile
    int w  = (bid >> 1) & 127;
    int b  = bid >> 8;
    int t  = threadIdx.x;
    int lh = t & 63;
    int c0 = (t >> 6) * 16;
    const float* fp = f + (((b*64)*128 + w)*128) + ht*64 + lh;
#pragma unroll
    for (int i = 0; i < 16; i++) {
        int c = c0 + i;
        tile[c][lh] = fp[c*16384];
    }
    __syncthreads();
    int lc = t & 63;
    int h0 = (t >> 6) * 16;
    float* op = feat + (((b*128 + w)*128) + ht*64)*64 + lc;
#pragma unroll
    for (int i = 0; i < 16; i++) {
        int hr = h0 + i;
        op[hr*64] = tile[lc][hr];
    }
}

// ---------------- w_dsc (O,C,K) -> wT[k][c][o] ----------------
__global__ void k_wt(const float* __restrict__ w_dsc, float* __restrict__ wT) {
    int i = blockIdx.x*256 + threadIdx.x;       // < 36864
    if (i >= 9*64*64) return;
    int o = i & 63;
    int c = (i >> 6) & 63;
    int k = i >> 12;
    wT[i] = w_dsc[(o*64 + c)*9 + k];
}

// ---------------- w_off (18,64,3,3) -> wP[g][tap][i][c]  (ck = g*3+i) ----------------
__global__ void k_wp(const float* __restrict__ w_off, float* __restrict__ wP) {
    int i = blockIdx.x*256 + threadIdx.x;       // < 5184
    if (i >= 3*9*3*64) return;
    int c   = i & 63;
    int r   = i >> 6;          // r = (g*9+tap)*3 + ii
    int ii  = r % 3;
    int tap = (r / 3) % 9;
    int g   = r / 27;
    int ck  = g*3 + ii;
    wP[i] = w_off[ck*576 + c*9 + tap];
}

// ---------------- 3x3 conv (9 out ch, ck-split x3) + BN stats ----------------
__global__ __launch_bounds__(256) void k_conv_off(const float* __restrict__ feat,
                                                  const float* __restrict__ wP,
                                                  const float* __restrict__ b_off,
                                                  float* __restrict__ off_pre,
                                                  float* __restrict__ bnstats) {
    __shared__ float wred[4][6];
    int t  = threadIdx.x;
    int g  = blockIdx.x >> 9;          // ck group 0..2 (wave-uniform)
    int pb = blockIdx.x & 511;
    int p  = pb*256 + t;
    int b  = p >> 14;
    int w  = (p >> 7) & 127;
    int h  = p & 127;

    float acc0 = b_off[g*3+0];
    float acc1 = b_off[g*3+1];
    float acc2 = b_off[g*3+2];

    const float*  fb  = feat + ((size_t)b << 20);           // b*128*128*64
    const float4* wp4 = (const float4*)(wP + g*9*3*64);     // uniform -> scalar loads

#pragma unroll
    for (int dw = -1; dw <= 1; dw++) {
        int wy = w + dw;
        if ((unsigned)wy < 128u) {
#pragma unroll
            for (int dh = -1; dh <= 1; dh++) {
                int hx = h + dh;
                if ((unsigned)hx < 128u) {
                    const int tap = (dw+1)*3 + (dh+1);
                    const float4* fp = (const float4*)(fb + (wy*128 + hx)*64);
                    const float4* wt = wp4 + tap*48;        // [ii][cb16]
#pragma unroll
                    for (int cb = 0; cb < 16; cb++) {
                        float4 v  = fp[cb];
                        float4 w0 = wt[cb];
                        float4 w1 = wt[16+cb];
                        float4 w2 = wt[32+cb];
                        acc0 += v.x*w0.x + v.y*w0.y + v.z*w0.z + v.w*w0.w;
                        acc1 += v.x*w1.x + v.y*w1.y + v.z*w1.z + v.w*w1.w;
                        acc2 += v.x*w2.x + v.y*w2.y + v.z*w2.z + v.w*w2.w;
                    }
                }
            }
        }
    }

    int pixoff = (w << 7) + h;
    off_pre[((b*9 + g*3+0) << 14) + pixoff] = acc0;
    off_pre[((b*9 + g*3+1) << 14) + pixoff] = acc1;
    off_pre[((b*9 + g*3+2) << 14) + pixoff] = acc2;

    // BN stats: wave reduce -> block reduce -> atomics
    float r0=acc0, r1=acc1, r2=acc2;
    float q0=acc0*acc0, q1=acc1*acc1, q2=acc2*acc2;
    for (int off = 32; off; off >>= 1) {
        r0 += __shfl_down(r0, off); q0 += __shfl_down(q0, off);
        r1 += __shfl_down(r1, off); q1 += __shfl_down(q1, off);
        r2 += __shfl_down(r2, off); q2 += __shfl_down(q2, off);
    }
    int wid = t >> 6;
    if ((t & 63) == 0) {
        wred[wid][0]=r0; wred[wid][1]=r1; wred[wid][2]=r2;
        wred[wid][3]=q0; wred[wid][4]=q1; wred[wid][5]=q2;
    }
    __syncthreads();
    if (t < 6) {
        float s = wred[0][t] + wred[1][t] + wred[2][t] + wred[3][t];
        atomicAdd(&bnstats[(g*3 + (t < 3 ? t : t-3))*2 + (t < 3 ? 0 : 1)], s);
    }
}

// ---------------- BN finalize ----------------
__global__ void k_bn_fin(const float* __restrict__ bnstats,
                         const float* __restrict__ bn_gamma,
                         const float* __restrict__ bn_beta,
                         float* __restrict__ bnAB) {
    int t = threadIdx.x;
    if (t < 9) {
        float n    = (float)NPIX;
        float mean = bnstats[t*2] / n;
        float var  = bnstats[t*2+1] / n - mean*mean;
        float A    = bn_gamma[t] / sqrtf(var + EPS_);
        bnAB[t*2]   = A;
        bnAB[t*2+1] = bn_beta[t] - mean * A;
    }
}

// ---------------- fused: BN+tanh+cumsum offsets, bilinear sample, strip conv, GN stats ----------------
__global__ __launch_bounds__(256) void k_sample_dsc(const float* __restrict__ feat,
                                                    const float* __restrict__ off_pre,
                                                    const float* __restrict__ bnAB,
                                                    const float* __restrict__ wT,
                                                    const float* __restrict__ b_dsc,
                                                    float* __restrict__ xpre,
                                                    float* __restrict__ gstats) {
    __shared__ float ynew[9][128];
    __shared__ float wk[64][68];     // [c][o]
    __shared__ float samp[128][68];  // [h][c]
    __shared__ float red[16][2];

    int t = threadIdx.x;
    int bid = blockIdx.x;
    int b = bid >> 7; int w = bid & 127;

    if (t < 128) {
        int h = t;
        float y[9];
#pragma unroll
        for (int ck = 0; ck < 9; ck++) {
            float v = off_pre[((b*9+ck) << 14) + (w << 7) + h];
            y[ck] = tanhf(bnAB[ck*2]*v + bnAB[ck*2+1]);
        }
        float ofn[9];
        ofn[4] = 0.f;
        ofn[5] = y[5]; ofn[6] = y[5]+y[6]; ofn[7] = y[5]+y[6]+y[7];
        ofn[3] = y[3]; ofn[2] = y[3]+y[2]; ofn[1] = y[3]+y[2]+y[1];
        ofn[0] = y[0]; ofn[8] = y[8];
#pragma unroll
        for (int k = 0; k < 9; k++) ynew[k][h] = (float)w + ofn[k];
    }
    if (t < 16) { red[t][0] = 0.f; red[t][1] = 0.f; }

    float acc[4][8];
#pragma unroll
    for (int i = 0; i < 4; i++)
#pragma unroll
        for (int j = 0; j < 8; j++) acc[i][j] = 0.f;

    int og = (t & 15) * 4;   // 4 output channels (one GN group)
    int q  = t >> 4;         // 16 h-slices
    int h0 = q * 8;

    __syncthreads();

    for (int k = 0; k < 9; k++) {
        // stage weight slice [c][o]
        const float* wkg = wT + k*4096;
        for (int i = t; i < 4096; i += 256)
            wk[i >> 6][i & 63] = wkg[i];

        // stage bilinear samples for this k: thread -> (h, half-of-c)
        {
            int h  = t >> 1;
            int cb = (t & 1) * 32;
            float ys = ynew[k][h];
            float xs = (float)(k - 4 + h);
            int y0 = (int)floorf(ys);
            int x0 = k - 4 + h;
            int y0c = min(max(y0, 0), 127), y1c = min(max(y0+1, 0), 127);
            int x0c = min(max(x0, 0), 127), x1c = min(max(x0+1, 0), 127);
            float wa = ((float)y1c - ys) * ((float)x1c - xs);
            float wb = ((float)y1c - ys) * (xs - (float)x0c);
            float wc = (ys - (float)y0c) * ((float)x1c - xs);
            float wd = (ys - (float)y0c) * (xs - (float)x0c);
            const float* pb  = feat + ((size_t)b << 20);
            const float* p00 = pb + (y0c*128 + x0c)*64 + cb;
            const float* p01 = pb + (y0c*128 + x1c)*64 + cb;
            const float* p10 = pb + (y1c*128 + x0c)*64 + cb;
            const float* p11 = pb + (y1c*128 + x1c)*64 + cb;
#pragma unroll
            for (int cc = 0; cc < 32; cc += 4) {
                float4 a  = *(const float4*)(p00+cc);
                float4 b4 = *(const float4*)(p01+cc);
                float4 c4 = *(const float4*)(p10+cc);
                float4 d4 = *(const float4*)(p11+cc);
                float4 r;
                r.x = a.x*wa + b4.x*wb + c4.x*wc + d4.x*wd;
                r.y = a.y*wa + b4.y*wb + c4.y*wc + d4.y*wd;
                r.z = a.z*wa + b4.z*wb + c4.z*wc + d4.z*wd;
                r.w = a.w*wa + b4.w*wb + c4.w*wc + d4.w*wd;
                *(float4*)&samp[h][cb+cc] = r;
            }
        }
        __syncthreads();

        // accumulate: acc[oo][j] += samp[h0+j][c] * wk[c][og+oo]
#pragma unroll 4
        for (int cb = 0; cb < 64; cb += 4) {
            float4 w0 = *(const float4*)&wk[cb+0][og];
            float4 w1 = *(const float4*)&wk[cb+1][og];
            float4 w2 = *(const float4*)&wk[cb+2][og];
            float4 w3 = *(const float4*)&wk[cb+3][og];
#pragma unroll
            for (int j = 0; j < 8; j++) {
                float4 s = *(const float4*)&samp[h0+j][cb];
                acc[0][j] += s.x*w0.x + s.y*w1.x + s.z*w2.x + s.w*w3.x;
                acc[1][j] += s.x*w0.y + s.y*w1.y + s.z*w2.y + s.w*w3.y;
                acc[2][j] += s.x*w0.z + s.y*w1.z + s.z*w2.z + s.w*w3.z;
                acc[3][j] += s.x*w0.w + s.y*w1.w + s.z*w2.w + s.w*w3.w;
            }
        }
        __syncthreads();
    }

    // epilogue: bias, GN partial stats, write xpre
    float s1 = 0.f, s2 = 0.f;
#pragma unroll
    for (int oo = 0; oo < 4; oo++) {
        float bias = b_dsc[og+oo];
#pragma unroll
        for (int j = 0; j < 8; j++) {
            float v = acc[oo][j] + bias;
            acc[oo][j] = v;
            s1 += v; s2 += v*v;
        }
    }
    atomicAdd(&red[t & 15][0], s1);
    atomicAdd(&red[t & 15][1], s2);
#pragma unroll
    for (int oo = 0; oo < 4; oo++) {
        float* xp = xpre + (((b*64 + og + oo)*128 + w) << 7) + h0;
        *(float4*)(xp+0) = make_float4(acc[oo][0], acc[oo][1], acc[oo][2], acc[oo][3]);
        *(float4*)(xp+4) = make_float4(acc[oo][4], acc[oo][5], acc[oo][6], acc[oo][7]);
    }
    __syncthreads();
    if (t < 16) {
        atomicAdd(&gstats[(b*16 + t)*2],   red[t][0]);
        atomicAdd(&gstats[(b*16 + t)*2+1], red[t][1]);
    }
}

// ---------------- GN finalize ----------------
__global__ void k_gn_fin(const float* __restrict__ gstats, float* __restrict__ gnfin) {
    int t = threadIdx.x;
    if (t < 128) {
        float n    = 65536.f;           // 4 ch * 128 * 128
        float mean = gstats[t*2] / n;
        float var  = gstats[t*2+1] / n - mean*mean;
        gnfin[t*2]   = mean;
        gnfin[t*2+1] = 1.0f / sqrtf(var + EPS_);
    }
}

// ---------------- GN apply + ReLU ----------------
__global__ __launch_bounds__(256) void k_gn_apply(const float* __restrict__ xpre,
                                                  const float* __restrict__ gnfin,
                                                  const float* __restrict__ gn_gamma,
                                                  const float* __restrict__ gn_beta,
                                                  float* __restrict__ out) {
    int i4  = blockIdx.x*256 + threadIdx.x;
    int idx = i4 * 4;
    int o = (idx >> 14) & 63;
    int b = idx >> 20;
    int g = o >> 2;
    float mean = gnfin[(b*16+g)*2];
    float istd = gnfin[(b*16+g)*2+1];
    float ga = gn_gamma[o] * istd;
    float be = gn_beta[o] - mean * ga;
    float4 v = *(const float4*)(xpre + idx);
    v.x = fmaxf(v.x*ga + be, 0.f);
    v.y = fmaxf(v.y*ga + be, 0.f);
    v.z = fmaxf(v.z*ga + be, 0.f);
    v.w = fmaxf(v.w*ga + be, 0.f);
    *(float4*)(out + idx) = v;
}

extern "C" void kernel_launch(void* const* d_in, const int* in_sizes, int n_in,
                              void* d_out, int out_size, void* d_ws, size_t ws_size,
                              hipStream_t stream) {
    const float* f        = (const float*)d_in[0];
    const float* w_off    = (const float*)d_in[1];
    const float* b_off    = (const float*)d_in[2];
    const float* bn_gamma = (const float*)d_in[3];
    const float* bn_beta  = (const float*)d_in[4];
    const float* w_dsc    = (const float*)d_in[5];
    const float* b_dsc    = (const float*)d_in[6];
    const float* gn_gamma = (const float*)d_in[7];
    const float* gn_beta  = (const float*)d_in[8];

    float* ws      = (float*)d_ws;
    float* feat    = ws + FEAT_OFF;
    float* off_pre = ws + OFFPRE_OFF;
    float* xpre    = ws + XPRE_OFF;
    float* wT      = ws + WT_OFF;
    float* bnstats = ws + BNSTATS_OFF;
    float* bnAB    = ws + BNAB_OFF;
    float* gstats  = ws + GSTATS_OFF;
    float* gnfin   = ws + GNFIN_OFF;
    float* wP      = ws + WP_OFF;

    hipMemsetAsync(bnstats, 0, STATS_BYTES, stream);

    k_nhwc<<<2048, 256, 0, stream>>>(f, feat);
    k_wt<<<144, 256, 0, stream>>>(w_dsc, wT);
    k_wp<<<21, 256, 0, stream>>>(w_off, wP);
    k_conv_off<<<1536, 256, 0, stream>>>(feat, wP, b_off, off_pre, bnstats);
    k_bn_fin<<<1, 32, 0, stream>>>(bnstats, bn_gamma, bn_beta, bnAB);
    k_sample_dsc<<<1024, 256, 0, stream>>>(feat, off_pre, bnAB, wT, b_dsc, xpre, gstats);
    k_gn_fin<<<1, 128, 0, stream>>>(gstats, gnfin);
    k_gn_apply<<<8192, 256, 0, stream>>>(xpre, gnfin, gn_gamma, gn_beta, (float*)d_out);
}

// Round 5
// 356.368 us; speedup vs baseline: 2.0289x; 1.1608x over previous
//
#include <hip/hip_runtime.h>

#define B_   8
#define C_   64
#define W_   128
#define H_   128
#define K_   9
#define OUT_ 64
#define NPIX (B_*W_*H_)      // 131072
#define EPS_ 1e-5f

typedef __attribute__((ext_vector_type(8))) short bf16x8;
typedef __attribute__((ext_vector_type(4))) float f32x4;

// ---------------- workspace layout (floats) ----------------
#define FEAT_OFF    0                      // B*W*H*C  = 8388608  (NHWC f)
#define OFFPRE_OFF  8388608                // B*9*W*H  = 1179648
#define XPRE_OFF    9568256                // B*64*W*H = 8388608
#define WT_OFF      17956864               // 9*64*64 ushorts (bf16 w_dsc as [k][o][c])
#define BNSTATS_OFF 17993728               // 18  (sum,sumsq per ck)
#define BNAB_OFF    17993746               // 18  (A,B per ck)
#define GSTATS_OFF  17993764               // 256 (sum,sumsq per (b,g))
#define GNFIN_OFF   17994020               // 256 (mean,istd per (b,g))
#define WP_OFF      17994276               // 3*9*3*64 = 5184 (w_off repacked)
#define STATS_BYTES ((18+18+256+256)*sizeof(float))

__device__ __forceinline__ unsigned pack2bf(float a, float b) {
    union { float f; unsigned u; } ua, ub;
    ua.f = a; ub.f = b;
    unsigned x = ua.u, y = ub.u;
    x += 0x7fffu + ((x >> 16) & 1u);       // RNE to bf16
    y += 0x7fffu + ((y >> 16) & 1u);
    return (x >> 16) | (y & 0xffff0000u);
}

// ---------------- NCHW -> NHWC transpose of f ----------------
__global__ __launch_bounds__(256) void k_nhwc(const float* __restrict__ f,
                                              float* __restrict__ feat) {
    __shared__ float tile[64][65];
    int bid = blockIdx.x;
    int ht = bid & 1;            // 64-high h tile
    int w  = (bid >> 1) & 127;
    int b  = bid >> 8;
    int t  = threadIdx.x;
    int lh = t & 63;
    int c0 = (t >> 6) * 16;
    const float* fp = f + (((b*64)*128 + w)*128) + ht*64 + lh;
#pragma unroll
    for (int i = 0; i < 16; i++) {
        int c = c0 + i;
        tile[c][lh] = fp[c*16384];
    }
    __syncthreads();
    int lc = t & 63;
    int h0 = (t >> 6) * 16;
    float* op = feat + (((b*128 + w)*128) + ht*64)*64 + lc;
#pragma unroll
    for (int i = 0; i < 16; i++) {
        int hr = h0 + i;
        op[hr*64] = tile[lc][hr];
    }
}

// ---------------- w_dsc (O,C,K) -> wTbf[k][o][c] bf16 ----------------
__global__ void k_wt(const float* __restrict__ w_dsc, unsigned short* __restrict__ wTbf) {
    int i = blockIdx.x*256 + threadIdx.x;       // < 36864
    if (i >= 9*64*64) return;
    int c = i & 63;
    int o = (i >> 6) & 63;
    int k = i >> 12;
    union { float f; unsigned u; } v;
    v.f = w_dsc[(o*64 + c)*9 + k];
    unsigned x = v.u + 0x7fffu + ((v.u >> 16) & 1u);
    wTbf[i] = (unsigned short)(x >> 16);
}

// ---------------- w_off (18,64,3,3) -> wP[g][tap][i][c]  (ck = g*3+i) ----------------
__global__ void k_wp(const float* __restrict__ w_off, float* __restrict__ wP) {
    int i = blockIdx.x*256 + threadIdx.x;       // < 5184
    if (i >= 3*9*3*64) return;
    int c   = i & 63;
    int r   = i >> 6;          // r = (g*9+tap)*3 + ii
    int ii  = r % 3;
    int tap = (r / 3) % 9;
    int g   = r / 27;
    int ck  = g*3 + ii;
    wP[i] = w_off[ck*576 + c*9 + tap];
}

// ---------------- 3x3 conv (9 out ch, ck-split x3) + BN stats ----------------
__global__ __launch_bounds__(256) void k_conv_off(const float* __restrict__ feat,
                                                  const float* __restrict__ wP,
                                                  const float* __restrict__ b_off,
                                                  float* __restrict__ off_pre,
                                                  float* __restrict__ bnstats) {
    __shared__ float wred[4][6];
    int t  = threadIdx.x;
    int g  = blockIdx.x >> 9;          // ck group 0..2 (wave-uniform)
    int pb = blockIdx.x & 511;
    int p  = pb*256 + t;
    int b  = p >> 14;
    int w  = (p >> 7) & 127;
    int h  = p & 127;

    float acc0 = b_off[g*3+0];
    float acc1 = b_off[g*3+1];
    float acc2 = b_off[g*3+2];

    const float*  fb  = feat + ((size_t)b << 20);           // b*128*128*64
    const float4* wp4 = (const float4*)(wP + g*9*3*64);     // uniform -> scalar loads

#pragma unroll
    for (int dw = -1; dw <= 1; dw++) {
        int wy = w + dw;
        if ((unsigned)wy < 128u) {
#pragma unroll
            for (int dh = -1; dh <= 1; dh++) {
                int hx = h + dh;
                if ((unsigned)hx < 128u) {
                    const int tap = (dw+1)*3 + (dh+1);
                    const float4* fp = (const float4*)(fb + (wy*128 + hx)*64);
                    const float4* wt = wp4 + tap*48;        // [ii][cb16]
#pragma unroll
                    for (int cb = 0; cb < 16; cb++) {
                        float4 v  = fp[cb];
                        float4 w0 = wt[cb];
                        float4 w1 = wt[16+cb];
                        float4 w2 = wt[32+cb];
                        acc0 += v.x*w0.x + v.y*w0.y + v.z*w0.z + v.w*w0.w;
                        acc1 += v.x*w1.x + v.y*w1.y + v.z*w1.z + v.w*w1.w;
                        acc2 += v.x*w2.x + v.y*w2.y + v.z*w2.z + v.w*w2.w;
                    }
                }
            }
        }
    }

    int pixoff = (w << 7) + h;
    off_pre[((b*9 + g*3+0) << 14) + pixoff] = acc0;
    off_pre[((b*9 + g*3+1) << 14) + pixoff] = acc1;
    off_pre[((b*9 + g*3+2) << 14) + pixoff] = acc2;

    // BN stats: wave reduce -> block reduce -> atomics
    float r0=acc0, r1=acc1, r2=acc2;
    float q0=acc0*acc0, q1=acc1*acc1, q2=acc2*acc2;
    for (int off = 32; off; off >>= 1) {
        r0 += __shfl_down(r0, off); q0 += __shfl_down(q0, off);
        r1 += __shfl_down(r1, off); q1 += __shfl_down(q1, off);
        r2 += __shfl_down(r2, off); q2 += __shfl_down(q2, off);
    }
    int wid = t >> 6;
    if ((t & 63) == 0) {
        wred[wid][0]=r0; wred[wid][1]=r1; wred[wid][2]=r2;
        wred[wid][3]=q0; wred[wid][4]=q1; wred[wid][5]=q2;
    }
    __syncthreads();
    if (t < 6) {
        float s = wred[0][t] + wred[1][t] + wred[2][t] + wred[3][t];
        atomicAdd(&bnstats[(g*3 + (t < 3 ? t : t-3))*2 + (t < 3 ? 0 : 1)], s);
    }
}

// ---------------- BN finalize ----------------
__global__ void k_bn_fin(const float* __restrict__ bnstats,
                         const float* __restrict__ bn_gamma,
                         const float* __restrict__ bn_beta,
                         float* __restrict__ bnAB) {
    int t = threadIdx.x;
    if (t < 9) {
        float n    = (float)NPIX;
        float mean = bnstats[t*2] / n;
        float var  = bnstats[t*2+1] / n - mean*mean;
        float A    = bn_gamma[t] / sqrtf(var + EPS_);
        bnAB[t*2]   = A;
        bnAB[t*2+1] = bn_beta[t] - mean * A;
    }
}

// ---------------- fused: offsets, bilinear sample (bf16), MFMA strip conv, GN stats ----------------
__global__ __launch_bounds__(256) void k_sample_dsc(const float* __restrict__ feat,
                                                    const float* __restrict__ off_pre,
                                                    const float* __restrict__ bnAB,
                                                    const unsigned short* __restrict__ wTbf,
                                                    const float* __restrict__ b_dsc,
                                                    float* __restrict__ xpre,
                                                    float* __restrict__ gstats) {
    __shared__ __align__(16) unsigned char lds_samp[128*128]; // [h][c] bf16, XOR-swizzled rows
    __shared__ __align__(16) unsigned char lds_wk[64*128];    // [o][c] bf16, XOR-swizzled rows
    __shared__ float ynew[9][128];
    __shared__ float red[16][2];

    int t = threadIdx.x;
    int b = blockIdx.x >> 7, w = blockIdx.x & 127;

    if (t < 128) {
        int h = t;
        float y[9];
#pragma unroll
        for (int ck = 0; ck < 9; ck++) {
            float v = off_pre[((b*9+ck) << 14) + (w << 7) + h];
            y[ck] = tanhf(bnAB[ck*2]*v + bnAB[ck*2+1]);
        }
        float ofn[9];
        ofn[4] = 0.f;
        ofn[5] = y[5]; ofn[6] = y[5]+y[6]; ofn[7] = y[5]+y[6]+y[7];
        ofn[3] = y[3]; ofn[2] = y[3]+y[2]; ofn[1] = y[3]+y[2]+y[1];
        ofn[0] = y[0]; ofn[8] = y[8];
#pragma unroll
        for (int k = 0; k < 9; k++) ynew[k][h] = (float)w + ofn[k];
    }
    if (t < 16) { red[t][0] = 0.f; red[t][1] = 0.f; }

    f32x4 acc[2][4];
#pragma unroll
    for (int mi = 0; mi < 2; mi++)
#pragma unroll
        for (int ni = 0; ni < 4; ni++) {
            acc[mi][ni][0] = 0.f; acc[mi][ni][1] = 0.f;
            acc[mi][ni][2] = 0.f; acc[mi][ni][3] = 0.f;
        }

    int lane = t & 63, wv = t >> 6;
    int m0 = wv * 32;                 // wave's 32-row M tile
    int lm = lane & 15, lk = lane >> 4;
    int hs = t >> 1;                  // sampling row
    int c0 = (t & 1) * 32;            // sampling channel half

    __syncthreads();

    for (int k = 0; k < 9; k++) {
        if (k) __syncthreads();       // previous iter's MFMA reads done

        // ---- stage weight k-slice [64 o][64 c] bf16 into swizzled LDS ----
        {
            const uint4* src = (const uint4*)(wTbf + (k << 12));
#pragma unroll
            for (int i = 0; i < 2; i++) {
                int ci = t + i*256;                 // 0..511 16B chunks
                uint4 v = src[ci];
                int o  = ci >> 3;
                int cb = (ci & 7) << 4;
                *(uint4*)(lds_wk + o*128 + (cb ^ ((o & 7) << 4))) = v;
            }
        }

        // ---- bilinear sample row hs, channels c0..c0+31 -> bf16 LDS ----
        {
            float ys = ynew[k][hs];
            int   x0 = k - 4 + hs;
            float xs = (float)x0;
            int y0  = (int)floorf(ys);
            int y0c = min(max(y0, 0), 127),   y1c = min(max(y0+1, 0), 127);
            int x0c = min(max(x0, 0), 127),   x1c = min(max(x0+1, 0), 127);
            float wa = ((float)y1c - ys) * ((float)x1c - xs);
            float wb = ((float)y1c - ys) * (xs - (float)x0c);
            float wc = (ys - (float)y0c) * ((float)x1c - xs);
            float wd = (ys - (float)y0c) * (xs - (float)x0c);
            const float* pb  = feat + ((size_t)b << 20);
            const float* p00 = pb + (y0c*128 + x0c)*64 + c0;
            const float* p01 = pb + (y0c*128 + x1c)*64 + c0;
            const float* p10 = pb + (y1c*128 + x0c)*64 + c0;
            const float* p11 = pb + (y1c*128 + x1c)*64 + c0;
#pragma unroll
            for (int ci = 0; ci < 4; ci++) {
                int cc = ci*8;
                float4 a0 = *(const float4*)(p00+cc), a1 = *(const float4*)(p00+cc+4);
                float4 b0 = *(const float4*)(p01+cc), b1 = *(const float4*)(p01+cc+4);
                float4 g0 = *(const float4*)(p10+cc), g1 = *(const float4*)(p10+cc+4);
                float4 d0 = *(const float4*)(p11+cc), d1 = *(const float4*)(p11+cc+4);
                float r0 = a0.x*wa + b0.x*wb + g0.x*wc + d0.x*wd;
                float r1 = a0.y*wa + b0.y*wb + g0.y*wc + d0.y*wd;
                float r2 = a0.z*wa + b0.z*wb + g0.z*wc + d0.z*wd;
                float r3 = a0.w*wa + b0.w*wb + g0.w*wc + d0.w*wd;
                float r4 = a1.x*wa + b1.x*wb + g1.x*wc + d1.x*wd;
                float r5 = a1.y*wa + b1.y*wb + g1.y*wc + d1.y*wd;
                float r6 = a1.z*wa + b1.z*wb + g1.z*wc + d1.z*wd;
                float r7 = a1.w*wa + b1.w*wb + g1.w*wc + d1.w*wd;
                uint4 u;
                u.x = pack2bf(r0, r1); u.y = pack2bf(r2, r3);
                u.z = pack2bf(r4, r5); u.w = pack2bf(r6, r7);
                *(uint4*)(lds_samp + hs*128 + ((c0*2 + ci*16) ^ ((hs & 7) << 4))) = u;
            }
        }
        __syncthreads();

        // ---- MFMA: acc[mi][ni] += A[32k-slice] * B ----
#pragma unroll
        for (int ks = 0; ks < 2; ks++) {
            bf16x8 af[2], bfr[4];
#pragma unroll
            for (int mi = 0; mi < 2; mi++) {
                int h = m0 + mi*16 + lm;
                af[mi] = *(const bf16x8*)(lds_samp + h*128 + ((ks*64 + lk*16) ^ ((h & 7) << 4)));
            }
#pragma unroll
            for (int ni = 0; ni < 4; ni++) {
                int o = ni*16 + lm;
                bfr[ni] = *(const bf16x8*)(lds_wk + o*128 + ((ks*64 + lk*16) ^ ((o & 7) << 4)));
            }
#pragma unroll
            for (int mi = 0; mi < 2; mi++)
#pragma unroll
                for (int ni = 0; ni < 4; ni++)
                    acc[mi][ni] = __builtin_amdgcn_mfma_f32_16x16x32_bf16(af[mi], bfr[ni], acc[mi][ni], 0, 0, 0);
        }
    }

    // ---- epilogue: bias, xpre write (C/D: row=lk*4+reg, col=lm), GN partial stats ----
#pragma unroll
    for (int ni = 0; ni < 4; ni++) {
        int o = ni*16 + lm;
        float bias = b_dsc[o];
        float s1 = 0.f, s2 = 0.f;
#pragma unroll
        for (int mi = 0; mi < 2; mi++) {
            float4 r;
            r.x = acc[mi][ni][0] + bias;
            r.y = acc[mi][ni][1] + bias;
            r.z = acc[mi][ni][2] + bias;
            r.w = acc[mi][ni][3] + bias;
            s1 += r.x + r.y + r.z + r.w;
            s2 += r.x*r.x + r.y*r.y + r.z*r.z + r.w*r.w;
            int h = m0 + mi*16 + lk*4;
            *(float4*)(xpre + (((b*64 + o) << 14) + (w << 7) + h)) = r;
        }
        s1 += __shfl_xor(s1, 1);  s1 += __shfl_xor(s1, 2);
        s1 += __shfl_xor(s1, 16); s1 += __shfl_xor(s1, 32);
        s2 += __shfl_xor(s2, 1);  s2 += __shfl_xor(s2, 2);
        s2 += __shfl_xor(s2, 16); s2 += __shfl_xor(s2, 32);
        if (lk == 0 && (lm & 3) == 0) {
            atomicAdd(&red[ni*4 + (lm >> 2)][0], s1);
            atomicAdd(&red[ni*4 + (lm >> 2)][1], s2);
        }
    }
    __syncthreads();
    if (t < 16) {
        atomicAdd(&gstats[(b*16 + t)*2],   red[t][0]);
        atomicAdd(&gstats[(b*16 + t)*2+1], red[t][1]);
    }
}

// ---------------- GN finalize ----------------
__global__ void k_gn_fin(const float* __restrict__ gstats, float* __restrict__ gnfin) {
    int t = threadIdx.x;
    if (t < 128) {
        float n    = 65536.f;           // 4 ch * 128 * 128
        float mean = gstats[t*2] / n;
        float var  = gstats[t*2+1] / n - mean*mean;
        gnfin[t*2]   = mean;
        gnfin[t*2+1] = 1.0f / sqrtf(var + EPS_);
    }
}

// ---------------- GN apply + ReLU ----------------
__global__ __launch_bounds__(256) void k_gn_apply(const float* __restrict__ xpre,
                                                  const float* __restrict__ gnfin,
                                                  const float* __restrict__ gn_gamma,
                                                  const float* __restrict__ gn_beta,
                                                  float* __restrict__ out) {
    int i4  = blockIdx.x*256 + threadIdx.x;
    int idx = i4 * 4;
    int o = (idx >> 14) & 63;
    int b = idx >> 20;
    int g = o >> 2;
    float mean = gnfin[(b*16+g)*2];
    float istd = gnfin[(b*16+g)*2+1];
    float ga = gn_gamma[o] * istd;
    float be = gn_beta[o] - mean * ga;
    float4 v = *(const float4*)(xpre + idx);
    v.x = fmaxf(v.x*ga + be, 0.f);
    v.y = fmaxf(v.y*ga + be, 0.f);
    v.z = fmaxf(v.z*ga + be, 0.f);
    v.w = fmaxf(v.w*ga + be, 0.f);
    *(float4*)(out + idx) = v;
}

extern "C" void kernel_launch(void* const* d_in, const int* in_sizes, int n_in,
                              void* d_out, int out_size, void* d_ws, size_t ws_size,
                              hipStream_t stream) {
    const float* f        = (const float*)d_in[0];
    const float* w_off    = (const float*)d_in[1];
    const float* b_off    = (const float*)d_in[2];
    const float* bn_gamma = (const float*)d_in[3];
    const float* bn_beta  = (const float*)d_in[4];
    const float* w_dsc    = (const float*)d_in[5];
    const float* b_dsc    = (const float*)d_in[6];
    const float* gn_gamma = (const float*)d_in[7];
    const float* gn_beta  = (const float*)d_in[8];

    float* ws      = (float*)d_ws;
    float* feat    = ws + FEAT_OFF;
    float* off_pre = ws + OFFPRE_OFF;
    float* xpre    = ws + XPRE_OFF;
    unsigned short* wTbf = (unsigned short*)(ws + WT_OFF);
    float* bnstats = ws + BNSTATS_OFF;
    float* bnAB    = ws + BNAB_OFF;
    float* gstats  = ws + GSTATS_OFF;
    float* gnfin   = ws + GNFIN_OFF;
    float* wP      = ws + WP_OFF;

    hipMemsetAsync(bnstats, 0, STATS_BYTES, stream);

    k_nhwc<<<2048, 256, 0, stream>>>(f, feat);
    k_wt<<<144, 256, 0, stream>>>(w_dsc, wTbf);
    k_wp<<<21, 256, 0, stream>>>(w_off, wP);
    k_conv_off<<<1536, 256, 0, stream>>>(feat, wP, b_off, off_pre, bnstats);
    k_bn_fin<<<1, 32, 0, stream>>>(bnstats, bn_gamma, bn_beta, bnAB);
    k_sample_dsc<<<1024, 256, 0, stream>>>(feat, off_pre, bnAB, wTbf, b_dsc, xpre, gstats);
    k_gn_fin<<<1, 128, 0, stream>>>(gstats, gnfin);
    k_gn_apply<<<8192, 256, 0, stream>>>(xpre, gnfin, gn_gamma, gn_beta, (float*)d_out);
}

// Round 8
// 182.900 us; speedup vs baseline: 3.9532x; 1.9484x over previous
//
#include <hip/hip_runtime.h>

#define B_   8
#define C_   64
#define W_   128
#define H_   128
#define K_   9
#define OUT_ 64
#define NPIX (B_*W_*H_)      // 131072
#define EPS_ 1e-5f

typedef __attribute__((ext_vector_type(8))) short bf16x8;
typedef __attribute__((ext_vector_type(4))) float f32x4;

// ---------------- workspace layout (float offsets) ----------------
// feat32 (fp32 NHWC, 32MB) is consumed by k_conv_off, then its space is
// REUSED as xpre (written later by k_sample_dsc). Safe within one launch.
#define FEAT32_OFF  0                      // B*W*H*C fp32 = 8388608
#define XPRE_OFF    0                      // aliases FEAT32 (feat32 dead by then)
#define FEATBF_OFF  8388608                // B*W*H*C bf16 = 8388608 ushorts (4194304 f)
#define OFFPRE_OFF  12582912               // B*9*W*H  = 1179648
#define WT_OFF      13762560               // 9*64*64 bf16 (18432 f)
#define WP_OFF      13780992               // 3*9*3*64 = 5184
#define BNSTATS_OFF 13786176               // 18
#define BNAB_OFF    13786194               // 18
#define GSTATS_OFF  13786212               // 256
#define GNFIN_OFF   13786468               // 256
#define STATS_BYTES ((18+18+256+256)*sizeof(float))

__device__ __forceinline__ unsigned pack2bf(float a, float b) {
    union { float f; unsigned u; } ua, ub;
    ua.f = a; ub.f = b;
    unsigned x = ua.u, y = ub.u;
    x += 0x7fffu + ((x >> 16) & 1u);       // RNE to bf16
    y += 0x7fffu + ((y >> 16) & 1u);
    return (x >> 16) | (y & 0xffff0000u);
}
__device__ __forceinline__ float bflo(unsigned u) {
    union { unsigned u; float f; } v; v.u = u << 16; return v.f;
}
__device__ __forceinline__ float bfhi(unsigned u) {
    union { unsigned u; float f; } v; v.u = u & 0xffff0000u; return v.f;
}

// ---------------- NCHW -> NHWC transpose of f (fp32 + bf16 copies) ----------------
__global__ __launch_bounds__(256) void k_nhwc(const float* __restrict__ f,
                                              float* __restrict__ feat32,
                                              unsigned short* __restrict__ featbf) {
    __shared__ float tile[64][65];
    int bid = blockIdx.x;
    int ht = bid & 1;            // 64-high h tile
    int w  = (bid >> 1) & 127;
    int b  = bid >> 8;
    int t  = threadIdx.x;
    int lh = t & 63;
    int c0 = (t >> 6) * 16;
    const float* fp = f + (((b*64)*128 + w)*128) + ht*64 + lh;
#pragma unroll
    for (int i = 0; i < 16; i++) {
        int c = c0 + i;
        tile[c][lh] = fp[c*16384];
    }
    __syncthreads();
    int lc = t & 63;
    int h0 = (t >> 6) * 16;
    size_t base = ((size_t)((b*128 + w)*128) + ht*64)*64 + lc;
    float* o32 = feat32 + base;
    unsigned short* obf = featbf + base;
#pragma unroll
    for (int i = 0; i < 16; i++) {
        int hr = h0 + i;
        float fv = tile[lc][hr];
        o32[(size_t)hr*64] = fv;
        union { float f; unsigned u; } v; v.f = fv;
        unsigned x = v.u + 0x7fffu + ((v.u >> 16) & 1u);
        obf[(size_t)hr*64] = (unsigned short)(x >> 16);
    }
}

// ---------------- w_dsc (O,C,K) -> wTbf[k][o][c] bf16 ----------------
__global__ void k_wt(const float* __restrict__ w_dsc, unsigned short* __restrict__ wTbf) {
    int i = blockIdx.x*256 + threadIdx.x;       // < 36864
    if (i >= 9*64*64) return;
    int c = i & 63;
    int o = (i >> 6) & 63;
    int k = i >> 12;
    union { float f; unsigned u; } v;
    v.f = w_dsc[(o*64 + c)*9 + k];
    unsigned x = v.u + 0x7fffu + ((v.u >> 16) & 1u);
    wTbf[i] = (unsigned short)(x >> 16);
}

// ---------------- w_off (18,64,3,3) -> wP[g][tap][i][c]  (ck = g*3+i) ----------------
__global__ void k_wp(const float* __restrict__ w_off, float* __restrict__ wP) {
    int i = blockIdx.x*256 + threadIdx.x;       // < 5184
    if (i >= 3*9*3*64) return;
    int c   = i & 63;
    int r   = i >> 6;          // r = (g*9+tap)*3 + ii
    int ii  = r % 3;
    int tap = (r / 3) % 9;
    int g   = r / 27;
    int ck  = g*3 + ii;
    wP[i] = w_off[ck*576 + c*9 + tap];
}

// ---------------- 3x3 conv (9 out ch, ck-split x3, fp32 feat) + BN stats ----------------
// fp32 input is REQUIRED here: the offset path feeds a discontinuous sampler
// (clamp boundaries at ys<0 / ys>=127); bf16-perturbed offsets flip samples
// across the boundary vs the reference (R7 failure, absmax 1.25).
__global__ __launch_bounds__(256) void k_conv_off(const float* __restrict__ feat,
                                                  const float* __restrict__ wP,
                                                  const float* __restrict__ b_off,
                                                  float* __restrict__ off_pre,
                                                  float* __restrict__ bnstats) {
    __shared__ float wred[4][6];
    int t  = threadIdx.x;
    int g  = blockIdx.x >> 9;          // ck group 0..2 (wave-uniform)
    int pb = blockIdx.x & 511;
    // XCD swizzle: b = pb&7 so each XCD works one batch's feat
    int newpb = (pb & 7) * 64 + (pb >> 3);
    int p  = newpb*256 + t;
    int b  = p >> 14;
    int w  = (p >> 7) & 127;
    int h  = p & 127;

    float acc0 = b_off[g*3+0];
    float acc1 = b_off[g*3+1];
    float acc2 = b_off[g*3+2];

    const float*  fb  = feat + ((size_t)b << 20);           // b*128*128*64
    const float4* wp4 = (const float4*)(wP + g*9*3*64);     // uniform -> scalar loads

#pragma unroll
    for (int dw = -1; dw <= 1; dw++) {
        int wy = w + dw;
        if ((unsigned)wy < 128u) {
#pragma unroll
            for (int dh = -1; dh <= 1; dh++) {
                int hx = h + dh;
                if ((unsigned)hx < 128u) {
                    const int tap = (dw+1)*3 + (dh+1);
                    const float4* fp = (const float4*)(fb + (wy*128 + hx)*64);
                    const float4* wt = wp4 + tap*48;        // [ii][cb16]
#pragma unroll
                    for (int cb = 0; cb < 16; cb++) {
                        float4 v  = fp[cb];
                        float4 w0 = wt[cb];
                        float4 w1 = wt[16+cb];
                        float4 w2 = wt[32+cb];
                        acc0 += v.x*w0.x + v.y*w0.y + v.z*w0.z + v.w*w0.w;
                        acc1 += v.x*w1.x + v.y*w1.y + v.z*w1.z + v.w*w1.w;
                        acc2 += v.x*w2.x + v.y*w2.y + v.z*w2.z + v.w*w2.w;
                    }
                }
            }
        }
    }

    int pixoff = (w << 7) + h;
    off_pre[((b*9 + g*3+0) << 14) + pixoff] = acc0;
    off_pre[((b*9 + g*3+1) << 14) + pixoff] = acc1;
    off_pre[((b*9 + g*3+2) << 14) + pixoff] = acc2;

    // BN stats: wave reduce -> block reduce -> atomics
    float r0=acc0, r1=acc1, r2=acc2;
    float q0=acc0*acc0, q1=acc1*acc1, q2=acc2*acc2;
    for (int off = 32; off; off >>= 1) {
        r0 += __shfl_down(r0, off); q0 += __shfl_down(q0, off);
        r1 += __shfl_down(r1, off); q1 += __shfl_down(q1, off);
        r2 += __shfl_down(r2, off); q2 += __shfl_down(q2, off);
    }
    int wid = t >> 6;
    if ((t & 63) == 0) {
        wred[wid][0]=r0; wred[wid][1]=r1; wred[wid][2]=r2;
        wred[wid][3]=q0; wred[wid][4]=q1; wred[wid][5]=q2;
    }
    __syncthreads();
    if (t < 6) {
        float s = wred[0][t] + wred[1][t] + wred[2][t] + wred[3][t];
        atomicAdd(&bnstats[(g*3 + (t < 3 ? t : t-3))*2 + (t < 3 ? 0 : 1)], s);
    }
}

// ---------------- BN finalize ----------------
__global__ void k_bn_fin(const float* __restrict__ bnstats,
                         const float* __restrict__ bn_gamma,
                         const float* __restrict__ bn_beta,
                         float* __restrict__ bnAB) {
    int t = threadIdx.x;
    if (t < 9) {
        float n    = (float)NPIX;
        float mean = bnstats[t*2] / n;
        float var  = bnstats[t*2+1] / n - mean*mean;
        float A    = bn_gamma[t] / sqrtf(var + EPS_);
        bnAB[t*2]   = A;
        bnAB[t*2+1] = bn_beta[t] - mean * A;
    }
}

// ---------------- fused: offsets, 2-tap y-lerp sample (bf16), MFMA strip conv, GN stats ----------------
__global__ __launch_bounds__(256) void k_sample_dsc(const unsigned short* __restrict__ featbf,
                                                    const float* __restrict__ off_pre,
                                                    const float* __restrict__ bnAB,
                                                    const unsigned short* __restrict__ wTbf,
                                                    const float* __restrict__ b_dsc,
                                                    float* __restrict__ xpre,
                                                    float* __restrict__ gstats) {
    __shared__ __align__(16) unsigned char lds_samp[128*128]; // [h][c] bf16, XOR-swizzled rows
    __shared__ __align__(16) unsigned char lds_wk[64*128];    // [o][c] bf16, XOR-swizzled rows
    __shared__ float ynew[9][128];
    __shared__ float red[16][2];

    int t = threadIdx.x;
    // XCD swizzle: 1024 blocks = 8 XCD x 128; each XCD owns one b
    int b = blockIdx.x & 7, w = blockIdx.x >> 3;

    if (t < 128) {
        int h = t;
        float y[9];
#pragma unroll
        for (int ck = 0; ck < 9; ck++) {
            float v = off_pre[((b*9+ck) << 14) + (w << 7) + h];
            y[ck] = tanhf(bnAB[ck*2]*v + bnAB[ck*2+1]);
        }
        float ofn[9];
        ofn[4] = 0.f;
        ofn[5] = y[5]; ofn[6] = y[5]+y[6]; ofn[7] = y[5]+y[6]+y[7];
        ofn[3] = y[3]; ofn[2] = y[3]+y[2]; ofn[1] = y[3]+y[2]+y[1];
        ofn[0] = y[0]; ofn[8] = y[8];
#pragma unroll
        for (int k = 0; k < 9; k++) ynew[k][h] = (float)w + ofn[k];
    }
    if (t < 16) { red[t][0] = 0.f; red[t][1] = 0.f; }

    f32x4 acc[2][4];
#pragma unroll
    for (int mi = 0; mi < 2; mi++)
#pragma unroll
        for (int ni = 0; ni < 4; ni++) {
            acc[mi][ni][0] = 0.f; acc[mi][ni][1] = 0.f;
            acc[mi][ni][2] = 0.f; acc[mi][ni][3] = 0.f;
        }

    int lane = t & 63, wv = t >> 6;
    int m0 = wv * 32;                 // wave's 32-row M tile
    int lm = lane & 15, lk = lane >> 4;
    int hs = t >> 1;                  // sampling row
    int cq = (t & 1) * 4;             // uint4 offset (32 ch half)

    __syncthreads();

    for (int k = 0; k < 9; k++) {
        if (k) __syncthreads();       // previous iter's MFMA reads done

        // ---- stage weight k-slice [64 o][64 c] bf16 into swizzled LDS ----
        {
            const uint4* src = (const uint4*)(wTbf + (k << 12));
#pragma unroll
            for (int i = 0; i < 2; i++) {
                int ci = t + i*256;                 // 0..511 16B chunks
                uint4 v = src[ci];
                int o  = ci >> 3;
                int cb = (ci & 7) << 4;
                *(uint4*)(lds_wk + o*128 + (cb ^ ((o & 7) << 4))) = v;
            }
        }

        // ---- 2-tap y-lerp sample, row hs, 32 ch -> bf16 LDS ----
        // x_s is integer -> x-weights are {1,0} in-bounds, exact 0 outside
        {
            int x0 = k - 4 + hs;
            unsigned char* dst = lds_samp + hs*128;
            int bcol0 = (t & 1) * 64;
            if ((unsigned)x0 < 127u) {
                float ys = ynew[k][hs];
                int y0  = (int)floorf(ys);
                int y0c = min(max(y0, 0), 127), y1c = min(max(y0+1, 0), 127);
                float wa = (float)y1c - ys;     // top tap weight
                float wc = ys - (float)y0c;     // bottom tap weight
                const unsigned short* pb = featbf + ((size_t)b << 20);
                const uint4* p0 = (const uint4*)(pb + (y0c*128 + x0)*64) + cq;
                const uint4* p1 = (const uint4*)(pb + (y1c*128 + x0)*64) + cq;
#pragma unroll
                for (int ci = 0; ci < 4; ci++) {
                    uint4 a = p0[ci], c = p1[ci];
                    uint4 u;
                    u.x = pack2bf(bflo(a.x)*wa + bflo(c.x)*wc, bfhi(a.x)*wa + bfhi(c.x)*wc);
                    u.y = pack2bf(bflo(a.y)*wa + bflo(c.y)*wc, bfhi(a.y)*wa + bfhi(c.y)*wc);
                    u.z = pack2bf(bflo(a.z)*wa + bflo(c.z)*wc, bfhi(a.z)*wa + bfhi(c.z)*wc);
                    u.w = pack2bf(bflo(a.w)*wa + bflo(c.w)*wc, bfhi(a.w)*wa + bfhi(c.w)*wc);
                    *(uint4*)(dst + ((bcol0 + ci*16) ^ ((hs & 7) << 4))) = u;
                }
            } else {
                uint4 z = make_uint4(0,0,0,0);
#pragma unroll
                for (int ci = 0; ci < 4; ci++)
                    *(uint4*)(dst + ((bcol0 + ci*16) ^ ((hs & 7) << 4))) = z;
            }
        }
        __syncthreads();

        // ---- MFMA: acc[mi][ni] += A[32k-slice] * B ----
#pragma unroll
        for (int ks = 0; ks < 2; ks++) {
            bf16x8 af[2], bfr[4];
#pragma unroll
            for (int mi = 0; mi < 2; mi++) {
                int h = m0 + mi*16 + lm;
                af[mi] = *(const bf16x8*)(lds_samp + h*128 + ((ks*64 + lk*16) ^ ((h & 7) << 4)));
            }
#pragma unroll
            for (int ni = 0; ni < 4; ni++) {
                int o = ni*16 + lm;
                bfr[ni] = *(const bf16x8*)(lds_wk + o*128 + ((ks*64 + lk*16) ^ ((o & 7) << 4)));
            }
#pragma unroll
            for (int mi = 0; mi < 2; mi++)
#pragma unroll
                for (int ni = 0; ni < 4; ni++)
                    acc[mi][ni] = __builtin_amdgcn_mfma_f32_16x16x32_bf16(af[mi], bfr[ni], acc[mi][ni], 0, 0, 0);
        }
    }

    // ---- epilogue: bias, xpre write (C/D: row=lk*4+reg, col=lm), GN partial stats ----
#pragma unroll
    for (int ni = 0; ni < 4; ni++) {
        int o = ni*16 + lm;
        float bias = b_dsc[o];
        float s1 = 0.f, s2 = 0.f;
#pragma unroll
        for (int mi = 0; mi < 2; mi++) {
            float4 r;
            r.x = acc[mi][ni][0] + bias;
            r.y = acc[mi][ni][1] + bias;
            r.z = acc[mi][ni][2] + bias;
            r.w = acc[mi][ni][3] + bias;
            s1 += r.x + r.y + r.z + r.w;
            s2 += r.x*r.x + r.y*r.y + r.z*r.z + r.w*r.w;
            int h = m0 + mi*16 + lk*4;
            *(float4*)(xpre + (((b*64 + o) << 14) + (w << 7) + h)) = r;
        }
        s1 += __shfl_xor(s1, 1);  s1 += __shfl_xor(s1, 2);
        s1 += __shfl_xor(s1, 16); s1 += __shfl_xor(s1, 32);
        s2 += __shfl_xor(s2, 1);  s2 += __shfl_xor(s2, 2);
        s2 += __shfl_xor(s2, 16); s2 += __shfl_xor(s2, 32);
        if (lk == 0 && (lm & 3) == 0) {
            atomicAdd(&red[ni*4 + (lm >> 2)][0], s1);
            atomicAdd(&red[ni*4 + (lm >> 2)][1], s2);
        }
    }
    __syncthreads();
    if (t < 16) {
        atomicAdd(&gstats[(b*16 + t)*2],   red[t][0]);
        atomicAdd(&gstats[(b*16 + t)*2+1], red[t][1]);
    }
}

// ---------------- GN finalize ----------------
__global__ void k_gn_fin(const float* __restrict__ gstats, float* __restrict__ gnfin) {
    int t = threadIdx.x;
    if (t < 128) {
        float n    = 65536.f;           // 4 ch * 128 * 128
        float mean = gstats[t*2] / n;
        float var  = gstats[t*2+1] / n - mean*mean;
        gnfin[t*2]   = mean;
        gnfin[t*2+1] = 1.0f / sqrtf(var + EPS_);
    }
}

// ---------------- GN apply + ReLU ----------------
__global__ __launch_bounds__(256) void k_gn_apply(const float* __restrict__ xpre,
                                                  const float* __restrict__ gnfin,
                                                  const float* __restrict__ gn_gamma,
                                                  const float* __restrict__ gn_beta,
                                                  float* __restrict__ out) {
    int i4  = blockIdx.x*256 + threadIdx.x;
    int idx = i4 * 4;
    int o = (idx >> 14) & 63;
    int b = idx >> 20;
    int g = o >> 2;
    float mean = gnfin[(b*16+g)*2];
    float istd = gnfin[(b*16+g)*2+1];
    float ga = gn_gamma[o] * istd;
    float be = gn_beta[o] - mean * ga;
    float4 v = *(const float4*)(xpre + idx);
    v.x = fmaxf(v.x*ga + be, 0.f);
    v.y = fmaxf(v.y*ga + be, 0.f);
    v.z = fmaxf(v.z*ga + be, 0.f);
    v.w = fmaxf(v.w*ga + be, 0.f);
    *(float4*)(out + idx) = v;
}

extern "C" void kernel_launch(void* const* d_in, const int* in_sizes, int n_in,
                              void* d_out, int out_size, void* d_ws, size_t ws_size,
                              hipStream_t stream) {
    const float* f        = (const float*)d_in[0];
    const float* w_off    = (const float*)d_in[1];
    const float* b_off    = (const float*)d_in[2];
    const float* bn_gamma = (const float*)d_in[3];
    const float* bn_beta  = (const float*)d_in[4];
    const float* w_dsc    = (const float*)d_in[5];
    const float* b_dsc    = (const float*)d_in[6];
    const float* gn_gamma = (const float*)d_in[7];
    const float* gn_beta  = (const float*)d_in[8];

    float* ws      = (float*)d_ws;
    float* feat32  = ws + FEAT32_OFF;
    float* xpre    = ws + XPRE_OFF;          // aliases feat32 (sequenced)
    unsigned short* featbf = (unsigned short*)(ws + FEATBF_OFF);
    float* off_pre = ws + OFFPRE_OFF;
    unsigned short* wTbf = (unsigned short*)(ws + WT_OFF);
    float* wP      = ws + WP_OFF;
    float* bnstats = ws + BNSTATS_OFF;
    float* bnAB    = ws + BNAB_OFF;
    float* gstats  = ws + GSTATS_OFF;
    float* gnfin   = ws + GNFIN_OFF;

    hipMemsetAsync(bnstats, 0, STATS_BYTES, stream);

    k_nhwc<<<2048, 256, 0, stream>>>(f, feat32, featbf);
    k_wt<<<144, 256, 0, stream>>>(w_dsc, wTbf);
    k_wp<<<21, 256, 0, stream>>>(w_off, wP);
    k_conv_off<<<1536, 256, 0, stream>>>(feat32, wP, b_off, off_pre, bnstats);
    k_bn_fin<<<1, 32, 0, stream>>>(bnstats, bn_gamma, bn_beta, bnAB);
    k_sample_dsc<<<1024, 256, 0, stream>>>(featbf, off_pre, bnAB, wTbf, b_dsc, xpre, gstats);
    k_gn_fin<<<1, 128, 0, stream>>>(gstats, gnfin);
    k_gn_apply<<<8192, 256, 0, stream>>>(xpre, gnfin, gn_gamma, gn_beta, (float*)d_out);
}

// Round 9
// 153.212 us; speedup vs baseline: 4.7192x; 1.1938x over previous
//
#include <hip/hip_runtime.h>

#define B_   8
#define C_   64
#define W_   128
#define H_   128
#define K_   9
#define OUT_ 64
#define NPIX (B_*W_*H_)      // 131072
#define EPS_ 1e-5f

typedef __attribute__((ext_vector_type(8))) short bf16x8;
typedef __attribute__((ext_vector_type(4))) float f32x4;

// ---------------- workspace layout (float offsets) ----------------
#define FEATBF_OFF  0                      // B*W*H*C bf16 = 8388608 ushorts (4194304 f)
#define XPRE_OFF    4194304                // B*64*W*H = 8388608
#define OFFPRE_OFF  12582912               // B*9*W*H  = 1179648
#define WT_OFF      13762560               // 9*64*64 bf16 (18432 f)
#define WP_OFF      13780992               // 3*64*27 = 5184 (w_off repacked)
#define BNSTATS_OFF 13786176               // 18
#define BNAB_OFF    13786194               // 18
#define GSTATS_OFF  13786212               // 256
#define GNFIN_OFF   13786468               // 256
#define STATS_BYTES ((18+18+256+256)*sizeof(float))

__device__ __forceinline__ unsigned pack2bf(float a, float b) {
    union { float f; unsigned u; } ua, ub;
    ua.f = a; ub.f = b;
    unsigned x = ua.u, y = ub.u;
    x += 0x7fffu + ((x >> 16) & 1u);       // RNE to bf16
    y += 0x7fffu + ((y >> 16) & 1u);
    return (x >> 16) | (y & 0xffff0000u);
}
__device__ __forceinline__ float bflo(unsigned u) {
    union { unsigned u; float f; } v; v.u = u << 16; return v.f;
}
__device__ __forceinline__ float bfhi(unsigned u) {
    union { unsigned u; float f; } v; v.u = u & 0xffff0000u; return v.f;
}

// ---------------- NCHW -> NHWC bf16 transpose of f (sampling path only) ----------------
__global__ __launch_bounds__(256) void k_nhwc(const float* __restrict__ f,
                                              unsigned short* __restrict__ featbf) {
    __shared__ float tile[64][65];
    int bid = blockIdx.x;
    int ht = bid & 1;            // 64-high h tile
    int w  = (bid >> 1) & 127;
    int b  = bid >> 8;
    int t  = threadIdx.x;
    int lh = t & 63;
    int c0 = (t >> 6) * 16;
    const float* fp = f + (((b*64)*128 + w)*128) + ht*64 + lh;
#pragma unroll
    for (int i = 0; i < 16; i++) {
        int c = c0 + i;
        tile[c][lh] = fp[c*16384];
    }
    __syncthreads();
    int lc = t & 63;
    int h0 = (t >> 6) * 16;
    unsigned short* obf = featbf + ((size_t)((b*128 + w)*128) + ht*64)*64 + lc;
#pragma unroll
    for (int i = 0; i < 16; i++) {
        int hr = h0 + i;
        union { float f; unsigned u; } v; v.f = tile[lc][hr];
        unsigned x = v.u + 0x7fffu + ((v.u >> 16) & 1u);
        obf[(size_t)hr*64] = (unsigned short)(x >> 16);
    }
}

// ---------------- w_dsc (O,C,K) -> wTbf[k][o][c] bf16 ----------------
__global__ void k_wt(const float* __restrict__ w_dsc, unsigned short* __restrict__ wTbf) {
    int i = blockIdx.x*256 + threadIdx.x;       // < 36864
    if (i >= 9*64*64) return;
    int c = i & 63;
    int o = (i >> 6) & 63;
    int k = i >> 12;
    union { float f; unsigned u; } v;
    v.f = w_dsc[(o*64 + c)*9 + k];
    unsigned x = v.u + 0x7fffu + ((v.u >> 16) & 1u);
    wTbf[i] = (unsigned short)(x >> 16);
}

// ---------------- w_off (18,64,3,3) -> wP[g][c][dw][ck][dh]  (ck = g*3+ii) ----------------
__global__ void k_wp(const float* __restrict__ w_off, float* __restrict__ wP) {
    int i = blockIdx.x*256 + threadIdx.x;       // < 5184
    if (i >= 3*64*27) return;
    int g   = i / 1728;
    int rem = i % 1728;
    int c   = rem / 27;
    int q   = rem % 27;
    int dw  = q / 9;
    int rr  = q % 9;
    int ii  = rr / 3;
    int dh  = rr % 3;
    int ck  = g*3 + ii;
    wP[i] = w_off[ck*576 + c*9 + dw*3 + dh];
}

// ---------------- 3x3 conv from RAW NCHW f (lane = h -> coalesced) + BN stats ----------------
// fp32 path REQUIRED (offset feeds a discontinuous sampler; see R7 failure).
// lane=h with NCHW gives 256B/wave coalesced loads (the NHWC version was
// 64 txns/load-instr -> 115us TA-bound, VALUBusy 17%).
__global__ __launch_bounds__(128) void k_conv_off(const float* __restrict__ f,
                                                  const float* __restrict__ wP,
                                                  const float* __restrict__ b_off,
                                                  float* __restrict__ off_pre,
                                                  float* __restrict__ bnstats) {
    __shared__ float wred[2][6];
    int t   = threadIdx.x;          // 0..127 = h
    int bid = blockIdx.x;
    int g   = bid >> 10;            // ck group 0..2 (wave-uniform)
    int r   = bid & 1023;
    int b   = r & 7;                // XCD swizzle: each XCD owns one batch
    int w   = r >> 3;               // 0..127 (wave-uniform)
    int h   = t;

    float em = (h == 0)   ? 0.f : 1.f;   // zero the dh=-1 tap at image edge
    float ep = (h == 127) ? 0.f : 1.f;   // zero the dh=+1 tap at image edge
    int   om = h + ((h == 0)   ? 0 : -1);
    int   op = h + ((h == 127) ? 0 : 1);

    const float* fb = f + (size_t)b*1048576 + (size_t)w*128;   // c-stride 16384
    const float* wg = wP + g*1728;                              // [c][27], uniform

    float acc0 = b_off[g*3+0];
    float acc1 = b_off[g*3+1];
    float acc2 = b_off[g*3+2];

#pragma unroll 2
    for (int c = 0; c < 64; c++) {
        const float* p   = fb + c*16384;
        const float* wcc = wg + c*27;
#pragma unroll
        for (int dw = -1; dw <= 1; dw++) {
            int wy = w + dw;
            if ((unsigned)wy < 128u) {           // uniform branch
                const float* q = p + dw*128;
                float v0 = q[om] * em;
                float v1 = q[h];
                float v2 = q[op] * ep;
                const float* ww = wcc + (dw+1)*9;
                acc0 += v0*ww[0] + v1*ww[1] + v2*ww[2];
                acc1 += v0*ww[3] + v1*ww[4] + v2*ww[5];
                acc2 += v0*ww[6] + v1*ww[7] + v2*ww[8];
            }
        }
    }

    int pixoff = (w << 7) + h;
    off_pre[((b*9 + g*3+0) << 14) + pixoff] = acc0;
    off_pre[((b*9 + g*3+1) << 14) + pixoff] = acc1;
    off_pre[((b*9 + g*3+2) << 14) + pixoff] = acc2;

    // BN stats: wave reduce -> block reduce (2 waves) -> atomics
    float r0=acc0, r1=acc1, r2=acc2;
    float q0=acc0*acc0, q1=acc1*acc1, q2=acc2*acc2;
    for (int off = 32; off; off >>= 1) {
        r0 += __shfl_down(r0, off); q0 += __shfl_down(q0, off);
        r1 += __shfl_down(r1, off); q1 += __shfl_down(q1, off);
        r2 += __shfl_down(r2, off); q2 += __shfl_down(q2, off);
    }
    int wid = t >> 6;
    if ((t & 63) == 0) {
        wred[wid][0]=r0; wred[wid][1]=r1; wred[wid][2]=r2;
        wred[wid][3]=q0; wred[wid][4]=q1; wred[wid][5]=q2;
    }
    __syncthreads();
    if (t < 6) {
        float s = wred[0][t] + wred[1][t];
        atomicAdd(&bnstats[(g*3 + (t < 3 ? t : t-3))*2 + (t < 3 ? 0 : 1)], s);
    }
}

// ---------------- BN finalize ----------------
__global__ void k_bn_fin(const float* __restrict__ bnstats,
                         const float* __restrict__ bn_gamma,
                         const float* __restrict__ bn_beta,
                         float* __restrict__ bnAB) {
    int t = threadIdx.x;
    if (t < 9) {
        float n    = (float)NPIX;
        float mean = bnstats[t*2] / n;
        float var  = bnstats[t*2+1] / n - mean*mean;
        float A    = bn_gamma[t] / sqrtf(var + EPS_);
        bnAB[t*2]   = A;
        bnAB[t*2+1] = bn_beta[t] - mean * A;
    }
}

// ---------------- fused: offsets, 2-tap y-lerp sample (bf16), MFMA strip conv, GN stats ----------------
__global__ __launch_bounds__(256) void k_sample_dsc(const unsigned short* __restrict__ featbf,
                                                    const float* __restrict__ off_pre,
                                                    const float* __restrict__ bnAB,
                                                    const unsigned short* __restrict__ wTbf,
                                                    const float* __restrict__ b_dsc,
                                                    float* __restrict__ xpre,
                                                    float* __restrict__ gstats) {
    __shared__ __align__(16) unsigned char lds_samp[128*128]; // [h][c] bf16, XOR-swizzled rows
    __shared__ __align__(16) unsigned char lds_wk[64*128];    // [o][c] bf16, XOR-swizzled rows
    __shared__ float ynew[9][128];
    __shared__ float red[16][2];

    int t = threadIdx.x;
    // XCD swizzle: 1024 blocks = 8 XCD x 128; each XCD owns one b
    int b = blockIdx.x & 7, w = blockIdx.x >> 3;

    if (t < 128) {
        int h = t;
        float y[9];
#pragma unroll
        for (int ck = 0; ck < 9; ck++) {
            float v = off_pre[((b*9+ck) << 14) + (w << 7) + h];
            y[ck] = tanhf(bnAB[ck*2]*v + bnAB[ck*2+1]);
        }
        float ofn[9];
        ofn[4] = 0.f;
        ofn[5] = y[5]; ofn[6] = y[5]+y[6]; ofn[7] = y[5]+y[6]+y[7];
        ofn[3] = y[3]; ofn[2] = y[3]+y[2]; ofn[1] = y[3]+y[2]+y[1];
        ofn[0] = y[0]; ofn[8] = y[8];
#pragma unroll
        for (int k = 0; k < 9; k++) ynew[k][h] = (float)w + ofn[k];
    }
    if (t < 16) { red[t][0] = 0.f; red[t][1] = 0.f; }

    f32x4 acc[2][4];
#pragma unroll
    for (int mi = 0; mi < 2; mi++)
#pragma unroll
        for (int ni = 0; ni < 4; ni++) {
            acc[mi][ni][0] = 0.f; acc[mi][ni][1] = 0.f;
            acc[mi][ni][2] = 0.f; acc[mi][ni][3] = 0.f;
        }

    int lane = t & 63, wv = t >> 6;
    int m0 = wv * 32;                 // wave's 32-row M tile
    int lm = lane & 15, lk = lane >> 4;
    int hs = t >> 1;                  // sampling row
    int cq = (t & 1) * 4;             // uint4 offset (32 ch half)

    __syncthreads();

    for (int k = 0; k < 9; k++) {
        if (k) __syncthreads();       // previous iter's MFMA reads done

        // ---- stage weight k-slice [64 o][64 c] bf16 into swizzled LDS ----
        {
            const uint4* src = (const uint4*)(wTbf + (k << 12));
#pragma unroll
            for (int i = 0; i < 2; i++) {
                int ci = t + i*256;                 // 0..511 16B chunks
                uint4 v = src[ci];
                int o  = ci >> 3;
                int cb = (ci & 7) << 4;
                *(uint4*)(lds_wk + o*128 + (cb ^ ((o & 7) << 4))) = v;
            }
        }

        // ---- 2-tap y-lerp sample, row hs, 32 ch -> bf16 LDS ----
        // x_s is integer -> x-weights are {1,0} in-bounds, exact 0 outside
        {
            int x0 = k - 4 + hs;
            unsigned char* dst = lds_samp + hs*128;
            int bcol0 = (t & 1) * 64;
            if ((unsigned)x0 < 127u) {
                float ys = ynew[k][hs];
                int y0  = (int)floorf(ys);
                int y0c = min(max(y0, 0), 127), y1c = min(max(y0+1, 0), 127);
                float wa = (float)y1c - ys;     // top tap weight
                float wc = ys - (float)y0c;     // bottom tap weight
                const unsigned short* pb = featbf + ((size_t)b << 20);
                const uint4* p0 = (const uint4*)(pb + (y0c*128 + x0)*64) + cq;
                const uint4* p1 = (const uint4*)(pb + (y1c*128 + x0)*64) + cq;
#pragma unroll
                for (int ci = 0; ci < 4; ci++) {
                    uint4 a = p0[ci], c = p1[ci];
                    uint4 u;
                    u.x = pack2bf(bflo(a.x)*wa + bflo(c.x)*wc, bfhi(a.x)*wa + bfhi(c.x)*wc);
                    u.y = pack2bf(bflo(a.y)*wa + bflo(c.y)*wc, bfhi(a.y)*wa + bfhi(c.y)*wc);
                    u.z = pack2bf(bflo(a.z)*wa + bflo(c.z)*wc, bfhi(a.z)*wa + bfhi(c.z)*wc);
                    u.w = pack2bf(bflo(a.w)*wa + bflo(c.w)*wc, bfhi(a.w)*wa + bfhi(c.w)*wc);
                    *(uint4*)(dst + ((bcol0 + ci*16) ^ ((hs & 7) << 4))) = u;
                }
            } else {
                uint4 z = make_uint4(0,0,0,0);
#pragma unroll
                for (int ci = 0; ci < 4; ci++)
                    *(uint4*)(dst + ((bcol0 + ci*16) ^ ((hs & 7) << 4))) = z;
            }
        }
        __syncthreads();

        // ---- MFMA: acc[mi][ni] += A[32k-slice] * B ----
#pragma unroll
        for (int ks = 0; ks < 2; ks++) {
            bf16x8 af[2], bfr[4];
#pragma unroll
            for (int mi = 0; mi < 2; mi++) {
                int h = m0 + mi*16 + lm;
                af[mi] = *(const bf16x8*)(lds_samp + h*128 + ((ks*64 + lk*16) ^ ((h & 7) << 4)));
            }
#pragma unroll
            for (int ni = 0; ni < 4; ni++) {
                int o = ni*16 + lm;
                bfr[ni] = *(const bf16x8*)(lds_wk + o*128 + ((ks*64 + lk*16) ^ ((o & 7) << 4)));
            }
#pragma unroll
            for (int mi = 0; mi < 2; mi++)
#pragma unroll
                for (int ni = 0; ni < 4; ni++)
                    acc[mi][ni] = __builtin_amdgcn_mfma_f32_16x16x32_bf16(af[mi], bfr[ni], acc[mi][ni], 0, 0, 0);
        }
    }

    // ---- epilogue: bias, xpre write (C/D: row=lk*4+reg, col=lm), GN partial stats ----
#pragma unroll
    for (int ni = 0; ni < 4; ni++) {
        int o = ni*16 + lm;
        float bias = b_dsc[o];
        float s1 = 0.f, s2 = 0.f;
#pragma unroll
        for (int mi = 0; mi < 2; mi++) {
            float4 r;
            r.x = acc[mi][ni][0] + bias;
            r.y = acc[mi][ni][1] + bias;
            r.z = acc[mi][ni][2] + bias;
            r.w = acc[mi][ni][3] + bias;
            s1 += r.x + r.y + r.z + r.w;
            s2 += r.x*r.x + r.y*r.y + r.z*r.z + r.w*r.w;
            int h = m0 + mi*16 + lk*4;
            *(float4*)(xpre + (((b*64 + o) << 14) + (w << 7) + h)) = r;
        }
        s1 += __shfl_xor(s1, 1);  s1 += __shfl_xor(s1, 2);
        s1 += __shfl_xor(s1, 16); s1 += __shfl_xor(s1, 32);
        s2 += __shfl_xor(s2, 1);  s2 += __shfl_xor(s2, 2);
        s2 += __shfl_xor(s2, 16); s2 += __shfl_xor(s2, 32);
        if (lk == 0 && (lm & 3) == 0) {
            atomicAdd(&red[ni*4 + (lm >> 2)][0], s1);
            atomicAdd(&red[ni*4 + (lm >> 2)][1], s2);
        }
    }
    __syncthreads();
    if (t < 16) {
        atomicAdd(&gstats[(b*16 + t)*2],   red[t][0]);
        atomicAdd(&gstats[(b*16 + t)*2+1], red[t][1]);
    }
}

// ---------------- GN finalize ----------------
__global__ void k_gn_fin(const float* __restrict__ gstats, float* __restrict__ gnfin) {
    int t = threadIdx.x;
    if (t < 128) {
        float n    = 65536.f;           // 4 ch * 128 * 128
        float mean = gstats[t*2] / n;
        float var  = gstats[t*2+1] / n - mean*mean;
        gnfin[t*2]   = mean;
        gnfin[t*2+1] = 1.0f / sqrtf(var + EPS_);
    }
}

// ---------------- GN apply + ReLU ----------------
__global__ __launch_bounds__(256) void k_gn_apply(const float* __restrict__ xpre,
                                                  const float* __restrict__ gnfin,
                                                  const float* __restrict__ gn_gamma,
                                                  const float* __restrict__ gn_beta,
                                                  float* __restrict__ out) {
    int i4  = blockIdx.x*256 + threadIdx.x;
    int idx = i4 * 4;
    int o = (idx >> 14) & 63;
    int b = idx >> 20;
    int g = o >> 2;
    float mean = gnfin[(b*16+g)*2];
    float istd = gnfin[(b*16+g)*2+1];
    float ga = gn_gamma[o] * istd;
    float be = gn_beta[o] - mean * ga;
    float4 v = *(const float4*)(xpre + idx);
    v.x = fmaxf(v.x*ga + be, 0.f);
    v.y = fmaxf(v.y*ga + be, 0.f);
    v.z = fmaxf(v.z*ga + be, 0.f);
    v.w = fmaxf(v.w*ga + be, 0.f);
    *(float4*)(out + idx) = v;
}

extern "C" void kernel_launch(void* const* d_in, const int* in_sizes, int n_in,
                              void* d_out, int out_size, void* d_ws, size_t ws_size,
                              hipStream_t stream) {
    const float* f        = (const float*)d_in[0];
    const float* w_off    = (const float*)d_in[1];
    const float* b_off    = (const float*)d_in[2];
    const float* bn_gamma = (const float*)d_in[3];
    const float* bn_beta  = (const float*)d_in[4];
    const float* w_dsc    = (const float*)d_in[5];
    const float* b_dsc    = (const float*)d_in[6];
    const float* gn_gamma = (const float*)d_in[7];
    const float* gn_beta  = (const float*)d_in[8];

    float* ws      = (float*)d_ws;
    unsigned short* featbf = (unsigned short*)(ws + FEATBF_OFF);
    float* xpre    = ws + XPRE_OFF;
    float* off_pre = ws + OFFPRE_OFF;
    unsigned short* wTbf = (unsigned short*)(ws + WT_OFF);
    float* wP      = ws + WP_OFF;
    float* bnstats = ws + BNSTATS_OFF;
    float* bnAB    = ws + BNAB_OFF;
    float* gstats  = ws + GSTATS_OFF;
    float* gnfin   = ws + GNFIN_OFF;

    hipMemsetAsync(bnstats, 0, STATS_BYTES, stream);

    k_nhwc<<<2048, 256, 0, stream>>>(f, featbf);
    k_wt<<<144, 256, 0, stream>>>(w_dsc, wTbf);
    k_wp<<<21, 256, 0, stream>>>(w_off, wP);
    k_conv_off<<<3072, 128, 0, stream>>>(f, wP, b_off, off_pre, bnstats);
    k_bn_fin<<<1, 32, 0, stream>>>(bnstats, bn_gamma, bn_beta, bnAB);
    k_sample_dsc<<<1024, 256, 0, stream>>>(featbf, off_pre, bnAB, wTbf, b_dsc, xpre, gstats);
    k_gn_fin<<<1, 128, 0, stream>>>(gstats, gnfin);
    k_gn_apply<<<8192, 256, 0, stream>>>(xpre, gnfin, gn_gamma, gn_beta, (float*)d_out);
}

// Round 10
// 138.301 us; speedup vs baseline: 5.2280x; 1.1078x over previous
//
#include <hip/hip_runtime.h>

#define B_   8
#define C_   64
#define W_   128
#define H_   128
#define K_   9
#define OUT_ 64
#define NPIX (B_*W_*H_)      // 131072
#define EPS_ 1e-5f

typedef __attribute__((ext_vector_type(8))) short bf16x8;
typedef __attribute__((ext_vector_type(4))) float f32x4;

// ---------------- workspace layout (float offsets) ----------------
#define FEATBF_OFF  0                      // B*W*H*C bf16 = 8388608 ushorts (4194304 f)
#define XPRE_OFF    4194304                // B*64*W*H = 8388608
#define OFFPRE_OFF  12582912               // B*9*W*H  = 1179648
#define WT_OFF      13762560               // 9*64*64 bf16 (18432 f)
#define WP_OFF      13780992               // 64*81 = 5184 (w_off repacked [c][dw][ck][dh])
#define BNSTATS_OFF 13786176               // 18
#define BNAB_OFF    13786194               // 18
#define GSTATS_OFF  13786212               // 256
#define GNFIN_OFF   13786468               // 256
#define STATS_BYTES ((18+18+256+256)*sizeof(float))

__device__ __forceinline__ unsigned pack2bf(float a, float b) {
    union { float f; unsigned u; } ua, ub;
    ua.f = a; ub.f = b;
    unsigned x = ua.u, y = ub.u;
    x += 0x7fffu + ((x >> 16) & 1u);       // RNE to bf16
    y += 0x7fffu + ((y >> 16) & 1u);
    return (x >> 16) | (y & 0xffff0000u);
}
__device__ __forceinline__ float bflo(unsigned u) {
    union { unsigned u; float f; } v; v.u = u << 16; return v.f;
}
__device__ __forceinline__ float bfhi(unsigned u) {
    union { unsigned u; float f; } v; v.u = u & 0xffff0000u; return v.f;
}

// ---------------- NCHW -> NHWC bf16 transpose of f (sampling path only) ----------------
__global__ __launch_bounds__(256) void k_nhwc(const float* __restrict__ f,
                                              unsigned short* __restrict__ featbf) {
    __shared__ float tile[64][65];
    int bid = blockIdx.x;
    int ht = bid & 1;            // 64-high h tile
    int w  = (bid >> 1) & 127;
    int b  = bid >> 8;
    int t  = threadIdx.x;
    int lh = t & 63;
    int c0 = (t >> 6) * 16;
    const float* fp = f + (((b*64)*128 + w)*128) + ht*64 + lh;
#pragma unroll
    for (int i = 0; i < 16; i++) {
        int c = c0 + i;
        tile[c][lh] = fp[c*16384];
    }
    __syncthreads();
    int lc = t & 63;
    int h0 = (t >> 6) * 16;
    unsigned short* obf = featbf + ((size_t)((b*128 + w)*128) + ht*64)*64 + lc;
#pragma unroll
    for (int i = 0; i < 16; i++) {
        int hr = h0 + i;
        union { float f; unsigned u; } v; v.f = tile[lc][hr];
        unsigned x = v.u + 0x7fffu + ((v.u >> 16) & 1u);
        obf[(size_t)hr*64] = (unsigned short)(x >> 16);
    }
}

// ---------------- w_dsc (O,C,K) -> wTbf[k][o][c] bf16 ----------------
__global__ void k_wt(const float* __restrict__ w_dsc, unsigned short* __restrict__ wTbf) {
    int i = blockIdx.x*256 + threadIdx.x;       // < 36864
    if (i >= 9*64*64) return;
    int c = i & 63;
    int o = (i >> 6) & 63;
    int k = i >> 12;
    union { float f; unsigned u; } v;
    v.f = w_dsc[(o*64 + c)*9 + k];
    unsigned x = v.u + 0x7fffu + ((v.u >> 16) & 1u);
    wTbf[i] = (unsigned short)(x >> 16);
}

// ---------------- w_off (18,64,3,3) -> wP[c][dw][ck][dh] ----------------
__global__ void k_wp(const float* __restrict__ w_off, float* __restrict__ wP) {
    int i = blockIdx.x*256 + threadIdx.x;       // < 5184
    if (i >= 64*81) return;
    int c    = i / 81;
    int rem  = i % 81;
    int dw   = rem / 27;
    int rem2 = rem % 27;
    int ck   = rem2 / 3;
    int dh   = rem2 % 3;
    wP[i] = w_off[ck*576 + c*9 + dw*3 + dh];
}

// ---------------- 3x3 conv, ALL 9 ck per block (NCHW f, lane = h) + BN stats ----------------
// fp32 path REQUIRED (offset feeds a discontinuous sampler; see R7 failure).
// g-split merged (R9: 3 block-groups re-read same f rows -> 3x L2 demand,
// 27 FMA per 9 loads too thin to hide latency at 2 waves/SIMD).
__global__ __launch_bounds__(128) void k_conv_off(const float* __restrict__ f,
                                                  const float* __restrict__ wP,
                                                  const float* __restrict__ b_off,
                                                  float* __restrict__ off_pre,
                                                  float* __restrict__ bnstats) {
    __shared__ float wred[2][18];
    int t   = threadIdx.x;          // 0..127 = h
    int bid = blockIdx.x;
    int b   = bid & 7;              // XCD swizzle: each XCD owns one batch
    int w   = bid >> 3;             // 0..127 (wave-uniform)
    int h   = t;

    float em = (h == 0)   ? 0.f : 1.f;   // zero the dh=-1 tap at image edge
    float ep = (h == 127) ? 0.f : 1.f;   // zero the dh=+1 tap at image edge
    int   om = h + ((h == 0)   ? 0 : -1);
    int   op = h + ((h == 127) ? 0 : 1);

    const float* fb = f + (size_t)b*1048576 + (size_t)w*128;   // c-stride 16384

    float acc[9];
#pragma unroll
    for (int ck = 0; ck < 9; ck++) acc[ck] = b_off[ck];

#pragma unroll 2
    for (int c = 0; c < 64; c++) {
        const float* p  = fb + c*16384;
        const float* wc = wP + c*81;
#pragma unroll
        for (int dw = -1; dw <= 1; dw++) {
            int wy = w + dw;
            if ((unsigned)wy < 128u) {           // uniform branch
                const float* q = p + dw*128;
                float v0 = q[om] * em;
                float v1 = q[h];
                float v2 = q[op] * ep;
                const float* ww = wc + (dw+1)*27;
#pragma unroll
                for (int ck = 0; ck < 9; ck++)
                    acc[ck] += v0*ww[ck*3] + v1*ww[ck*3+1] + v2*ww[ck*3+2];
            }
        }
    }

    int pixoff = (w << 7) + h;
#pragma unroll
    for (int ck = 0; ck < 9; ck++)
        off_pre[((b*9 + ck) << 14) + pixoff] = acc[ck];

    // BN stats: wave reduce -> block reduce (2 waves) -> atomics
    float s[9], q[9];
#pragma unroll
    for (int ck = 0; ck < 9; ck++) { s[ck] = acc[ck]; q[ck] = acc[ck]*acc[ck]; }
    for (int off = 32; off; off >>= 1) {
#pragma unroll
        for (int ck = 0; ck < 9; ck++) {
            s[ck] += __shfl_down(s[ck], off);
            q[ck] += __shfl_down(q[ck], off);
        }
    }
    int wid = t >> 6;
    if ((t & 63) == 0) {
#pragma unroll
        for (int ck = 0; ck < 9; ck++) {
            wred[wid][ck]   = s[ck];
            wred[wid][9+ck] = q[ck];
        }
    }
    __syncthreads();
    if (t < 18) {
        float v = wred[0][t] + wred[1][t];
        int ck  = (t < 9) ? t : t-9;
        atomicAdd(&bnstats[ck*2 + (t < 9 ? 0 : 1)], v);
    }
}

// ---------------- BN finalize ----------------
__global__ void k_bn_fin(const float* __restrict__ bnstats,
                         const float* __restrict__ bn_gamma,
                         const float* __restrict__ bn_beta,
                         float* __restrict__ bnAB) {
    int t = threadIdx.x;
    if (t < 9) {
        float n    = (float)NPIX;
        float mean = bnstats[t*2] / n;
        float var  = bnstats[t*2+1] / n - mean*mean;
        float A    = bn_gamma[t] / sqrtf(var + EPS_);
        bnAB[t*2]   = A;
        bnAB[t*2+1] = bn_beta[t] - mean * A;
    }
}

// ---------------- fused: offsets, 2-tap y-lerp sample (bf16), MFMA strip conv, GN stats ----------------
__global__ __launch_bounds__(256) void k_sample_dsc(const unsigned short* __restrict__ featbf,
                                                    const float* __restrict__ off_pre,
                                                    const float* __restrict__ bnAB,
                                                    const unsigned short* __restrict__ wTbf,
                                                    const float* __restrict__ b_dsc,
                                                    float* __restrict__ xpre,
                                                    float* __restrict__ gstats) {
    __shared__ __align__(16) unsigned char lds_samp[128*128]; // [h][c] bf16, XOR-swizzled rows
    __shared__ __align__(16) unsigned char lds_wk[64*128];    // [o][c] bf16, XOR-swizzled rows
    __shared__ float ynew[9][128];
    __shared__ float red[16][2];

    int t = threadIdx.x;
    // XCD swizzle: 1024 blocks = 8 XCD x 128; each XCD owns one b
    int b = blockIdx.x & 7, w = blockIdx.x >> 3;

    if (t < 128) {
        int h = t;
        float y[9];
#pragma unroll
        for (int ck = 0; ck < 9; ck++) {
            float v = off_pre[((b*9+ck) << 14) + (w << 7) + h];
            y[ck] = tanhf(bnAB[ck*2]*v + bnAB[ck*2+1]);
        }
        float ofn[9];
        ofn[4] = 0.f;
        ofn[5] = y[5]; ofn[6] = y[5]+y[6]; ofn[7] = y[5]+y[6]+y[7];
        ofn[3] = y[3]; ofn[2] = y[3]+y[2]; ofn[1] = y[3]+y[2]+y[1];
        ofn[0] = y[0]; ofn[8] = y[8];
#pragma unroll
        for (int k = 0; k < 9; k++) ynew[k][h] = (float)w + ofn[k];
    }
    if (t < 16) { red[t][0] = 0.f; red[t][1] = 0.f; }

    f32x4 acc[2][4];
#pragma unroll
    for (int mi = 0; mi < 2; mi++)
#pragma unroll
        for (int ni = 0; ni < 4; ni++) {
            acc[mi][ni][0] = 0.f; acc[mi][ni][1] = 0.f;
            acc[mi][ni][2] = 0.f; acc[mi][ni][3] = 0.f;
        }

    int lane = t & 63, wv = t >> 6;
    int m0 = wv * 32;                 // wave's 32-row M tile
    int lm = lane & 15, lk = lane >> 4;
    int hs = t >> 1;                  // sampling row
    int cq = (t & 1) * 4;             // uint4 offset (32 ch half)

    __syncthreads();

    for (int k = 0; k < 9; k++) {
        if (k) __syncthreads();       // previous iter's MFMA reads done

        // ---- stage weight k-slice [64 o][64 c] bf16 into swizzled LDS ----
        {
            const uint4* src = (const uint4*)(wTbf + (k << 12));
#pragma unroll
            for (int i = 0; i < 2; i++) {
                int ci = t + i*256;                 // 0..511 16B chunks
                uint4 v = src[ci];
                int o  = ci >> 3;
                int cb = (ci & 7) << 4;
                *(uint4*)(lds_wk + o*128 + (cb ^ ((o & 7) << 4))) = v;
            }
        }

        // ---- 2-tap y-lerp sample, row hs, 32 ch -> bf16 LDS ----
        // x_s is integer -> x-weights are {1,0} in-bounds, exact 0 outside
        {
            int x0 = k - 4 + hs;
            unsigned char* dst = lds_samp + hs*128;
            int bcol0 = (t & 1) * 64;
            if ((unsigned)x0 < 127u) {
                float ys = ynew[k][hs];
                int y0  = (int)floorf(ys);
                int y0c = min(max(y0, 0), 127), y1c = min(max(y0+1, 0), 127);
                float wa = (float)y1c - ys;     // top tap weight
                float wc = ys - (float)y0c;     // bottom tap weight
                const unsigned short* pb = featbf + ((size_t)b << 20);
                const uint4* p0 = (const uint4*)(pb + (y0c*128 + x0)*64) + cq;
                const uint4* p1 = (const uint4*)(pb + (y1c*128 + x0)*64) + cq;
#pragma unroll
                for (int ci = 0; ci < 4; ci++) {
                    uint4 a = p0[ci], c = p1[ci];
                    uint4 u;
                    u.x = pack2bf(bflo(a.x)*wa + bflo(c.x)*wc, bfhi(a.x)*wa + bfhi(c.x)*wc);
                    u.y = pack2bf(bflo(a.y)*wa + bflo(c.y)*wc, bfhi(a.y)*wa + bfhi(c.y)*wc);
                    u.z = pack2bf(bflo(a.z)*wa + bflo(c.z)*wc, bfhi(a.z)*wa + bfhi(c.z)*wc);
                    u.w = pack2bf(bflo(a.w)*wa + bflo(c.w)*wc, bfhi(a.w)*wa + bfhi(c.w)*wc);
                    *(uint4*)(dst + ((bcol0 + ci*16) ^ ((hs & 7) << 4))) = u;
                }
            } else {
                uint4 z = make_uint4(0,0,0,0);
#pragma unroll
                for (int ci = 0; ci < 4; ci++)
                    *(uint4*)(dst + ((bcol0 + ci*16) ^ ((hs & 7) << 4))) = z;
            }
        }
        __syncthreads();

        // ---- MFMA: acc[mi][ni] += A[32k-slice] * B ----
#pragma unroll
        for (int ks = 0; ks < 2; ks++) {
            bf16x8 af[2], bfr[4];
#pragma unroll
            for (int mi = 0; mi < 2; mi++) {
                int h = m0 + mi*16 + lm;
                af[mi] = *(const bf16x8*)(lds_samp + h*128 + ((ks*64 + lk*16) ^ ((h & 7) << 4)));
            }
#pragma unroll
            for (int ni = 0; ni < 4; ni++) {
                int o = ni*16 + lm;
                bfr[ni] = *(const bf16x8*)(lds_wk + o*128 + ((ks*64 + lk*16) ^ ((o & 7) << 4)));
            }
#pragma unroll
            for (int mi = 0; mi < 2; mi++)
#pragma unroll
                for (int ni = 0; ni < 4; ni++)
                    acc[mi][ni] = __builtin_amdgcn_mfma_f32_16x16x32_bf16(af[mi], bfr[ni], acc[mi][ni], 0, 0, 0);
        }
    }

    // ---- epilogue: bias, xpre write (C/D: row=lk*4+reg, col=lm), GN partial stats ----
#pragma unroll
    for (int ni = 0; ni < 4; ni++) {
        int o = ni*16 + lm;
        float bias = b_dsc[o];
        float s1 = 0.f, s2 = 0.f;
#pragma unroll
        for (int mi = 0; mi < 2; mi++) {
            float4 r;
            r.x = acc[mi][ni][0] + bias;
            r.y = acc[mi][ni][1] + bias;
            r.z = acc[mi][ni][2] + bias;
            r.w = acc[mi][ni][3] + bias;
            s1 += r.x + r.y + r.z + r.w;
            s2 += r.x*r.x + r.y*r.y + r.z*r.z + r.w*r.w;
            int h = m0 + mi*16 + lk*4;
            *(float4*)(xpre + (((b*64 + o) << 14) + (w << 7) + h)) = r;
        }
        s1 += __shfl_xor(s1, 1);  s1 += __shfl_xor(s1, 2);
        s1 += __shfl_xor(s1, 16); s1 += __shfl_xor(s1, 32);
        s2 += __shfl_xor(s2, 1);  s2 += __shfl_xor(s2, 2);
        s2 += __shfl_xor(s2, 16); s2 += __shfl_xor(s2, 32);
        if (lk == 0 && (lm & 3) == 0) {
            atomicAdd(&red[ni*4 + (lm >> 2)][0], s1);
            atomicAdd(&red[ni*4 + (lm >> 2)][1], s2);
        }
    }
    __syncthreads();
    if (t < 16) {
        atomicAdd(&gstats[(b*16 + t)*2],   red[t][0]);
        atomicAdd(&gstats[(b*16 + t)*2+1], red[t][1]);
    }
}

// ---------------- GN finalize ----------------
__global__ void k_gn_fin(const float* __restrict__ gstats, float* __restrict__ gnfin) {
    int t = threadIdx.x;
    if (t < 128) {
        float n    = 65536.f;           // 4 ch * 128 * 128
        float mean = gstats[t*2] / n;
        float var  = gstats[t*2+1] / n - mean*mean;
        gnfin[t*2]   = mean;
        gnfin[t*2+1] = 1.0f / sqrtf(var + EPS_);
    }
}

// ---------------- GN apply + ReLU ----------------
__global__ __launch_bounds__(256) void k_gn_apply(const float* __restrict__ xpre,
                                                  const float* __restrict__ gnfin,
                                                  const float* __restrict__ gn_gamma,
                                                  const float* __restrict__ gn_beta,
                                                  float* __restrict__ out) {
    int i4  = blockIdx.x*256 + threadIdx.x;
    int idx = i4 * 4;
    int o = (idx >> 14) & 63;
    int b = idx >> 20;
    int g = o >> 2;
    float mean = gnfin[(b*16+g)*2];
    float istd = gnfin[(b*16+g)*2+1];
    float ga = gn_gamma[o] * istd;
    float be = gn_beta[o] - mean * ga;
    float4 v = *(const float4*)(xpre + idx);
    v.x = fmaxf(v.x*ga + be, 0.f);
    v.y = fmaxf(v.y*ga + be, 0.f);
    v.z = fmaxf(v.z*ga + be, 0.f);
    v.w = fmaxf(v.w*ga + be, 0.f);
    *(float4*)(out + idx) = v;
}

extern "C" void kernel_launch(void* const* d_in, const int* in_sizes, int n_in,
                              void* d_out, int out_size, void* d_ws, size_t ws_size,
                              hipStream_t stream) {
    const float* f        = (const float*)d_in[0];
    const float* w_off    = (const float*)d_in[1];
    const float* b_off    = (const float*)d_in[2];
    const float* bn_gamma = (const float*)d_in[3];
    const float* bn_beta  = (const float*)d_in[4];
    const float* w_dsc    = (const float*)d_in[5];
    const float* b_dsc    = (const float*)d_in[6];
    const float* gn_gamma = (const float*)d_in[7];
    const float* gn_beta  = (const float*)d_in[8];

    float* ws      = (float*)d_ws;
    unsigned short* featbf = (unsigned short*)(ws + FEATBF_OFF);
    float* xpre    = ws + XPRE_OFF;
    float* off_pre = ws + OFFPRE_OFF;
    unsigned short* wTbf = (unsigned short*)(ws + WT_OFF);
    float* wP      = ws + WP_OFF;
    float* bnstats = ws + BNSTATS_OFF;
    float* bnAB    = ws + BNAB_OFF;
    float* gstats  = ws + GSTATS_OFF;
    float* gnfin   = ws + GNFIN_OFF;

    hipMemsetAsync(bnstats, 0, STATS_BYTES, stream);

    k_nhwc<<<2048, 256, 0, stream>>>(f, featbf);
    k_wt<<<144, 256, 0, stream>>>(w_dsc, wTbf);
    k_wp<<<21, 256, 0, stream>>>(w_off, wP);
    k_conv_off<<<1024, 128, 0, stream>>>(f, wP, b_off, off_pre, bnstats);
    k_bn_fin<<<1, 32, 0, stream>>>(bnstats, bn_gamma, bn_beta, bnAB);
    k_sample_dsc<<<1024, 256, 0, stream>>>(featbf, off_pre, bnAB, wTbf, b_dsc, xpre, gstats);
    k_gn_fin<<<1, 128, 0, stream>>>(gstats, gnfin);
    k_gn_apply<<<8192, 256, 0, stream>>>(xpre, gnfin, gn_gamma, gn_beta, (float*)d_out);
}

// Round 12
// 124.141 us; speedup vs baseline: 5.8243x; 1.1141x over previous
//
#include <hip/hip_runtime.h>

#define B_   8
#define C_   64
#define W_   128
#define H_   128
#define K_   9
#define OUT_ 64
#define NPIX (B_*W_*H_)      // 131072
#define EPS_ 1e-5f

typedef __attribute__((ext_vector_type(8))) short bf16x8;
typedef __attribute__((ext_vector_type(4))) float f32x4;

// ---------------- workspace layout (float offsets) ----------------
#define FEATBF_OFF  0                      // B*W*H*C bf16 = 8388608 ushorts (4194304 f)
#define XPRE_OFF    4194304                // B*64*W*H = 8388608
#define OFFPRE_OFF  12582912               // B*9*W*H  = 1179648
#define OFFH_OFF    13762560               // 2*B*9*W*H = 2359296 (c-split partials)
#define WT_OFF      16121856               // 9*64*64 bf16 (18432 f)
#define WP_OFF      16140288               // 64*81 = 5184 (w_off repacked [c][dw][ck][dh])
#define BNSTATS_OFF 16145472               // 18
#define BNAB_OFF    16145490               // 18
#define GSTATS_OFF  16145508               // 256
#define GNFIN_OFF   16145764               // 256
#define STATS_BYTES ((18+18+256+256)*sizeof(float))

__device__ __forceinline__ unsigned pack2bf(float a, float b) {
    union { float f; unsigned u; } ua, ub;
    ua.f = a; ub.f = b;
    unsigned x = ua.u, y = ub.u;
    x += 0x7fffu + ((x >> 16) & 1u);       // RNE to bf16
    y += 0x7fffu + ((y >> 16) & 1u);
    return (x >> 16) | (y & 0xffff0000u);
}
__device__ __forceinline__ float bflo(unsigned u) {
    union { unsigned u; float f; } v; v.u = u << 16; return v.f;
}
__device__ __forceinline__ float bfhi(unsigned u) {
    union { unsigned u; float f; } v; v.u = u & 0xffff0000u; return v.f;
}

// ---------------- NCHW -> NHWC bf16 transpose of f (sampling path only) ----------------
__global__ __launch_bounds__(256) void k_nhwc(const float* __restrict__ f,
                                              unsigned short* __restrict__ featbf) {
    __shared__ float tile[64][65];
    int bid = blockIdx.x;
    int ht = bid & 1;            // 64-high h tile
    int w  = (bid >> 1) & 127;
    int b  = bid >> 8;
    int t  = threadIdx.x;
    int lh = t & 63;
    int c0 = (t >> 6) * 16;
    const float* fp = f + (((b*64)*128 + w)*128) + ht*64 + lh;
#pragma unroll
    for (int i = 0; i < 16; i++) {
        int c = c0 + i;
        tile[c][lh] = fp[c*16384];
    }
    __syncthreads();
    int lc = t & 63;
    int h0 = (t >> 6) * 16;
    unsigned short* obf = featbf + ((size_t)((b*128 + w)*128) + ht*64)*64 + lc;
#pragma unroll
    for (int i = 0; i < 16; i++) {
        int hr = h0 + i;
        union { float f; unsigned u; } v; v.f = tile[lc][hr];
        unsigned x = v.u + 0x7fffu + ((v.u >> 16) & 1u);
        obf[(size_t)hr*64] = (unsigned short)(x >> 16);
    }
}

// ---------------- w_dsc (O,C,K) -> wTbf[k][o][c] bf16 ----------------
__global__ void k_wt(const float* __restrict__ w_dsc, unsigned short* __restrict__ wTbf) {
    int i = blockIdx.x*256 + threadIdx.x;       // < 36864
    if (i >= 9*64*64) return;
    int c = i & 63;
    int o = (i >> 6) & 63;
    int k = i >> 12;
    union { float f; unsigned u; } v;
    v.f = w_dsc[(o*64 + c)*9 + k];
    unsigned x = v.u + 0x7fffu + ((v.u >> 16) & 1u);
    wTbf[i] = (unsigned short)(x >> 16);
}

// ---------------- w_off (18,64,3,3) -> wP[c][dw][ck][dh] ----------------
__global__ void k_wp(const float* __restrict__ w_off, float* __restrict__ wP) {
    int i = blockIdx.x*256 + threadIdx.x;       // < 5184
    if (i >= 64*81) return;
    int c    = i / 81;
    int rem  = i % 81;
    int dw   = rem / 27;
    int rem2 = rem % 27;
    int ck   = rem2 / 3;
    int dh   = rem2 % 3;
    wP[i] = w_off[ck*576 + c*9 + dw*3 + dh];
}

// ---------------- 3x3 conv, c-split x2 for occupancy (NCHW f, lane = h) ----------------
// fp32 path REQUIRED (offset feeds a discontinuous sampler; see R7 failure).
// NOTE: b_off deliberately dropped — a per-channel constant shifts the BN mean
// by itself, so A*off + (beta - mean*A) is invariant; bias cancels exactly.
// c-split: R10 showed 2 waves/SIMD can't hide the 9-load->81-FMA chain
// (Occupancy 18.8%, VALUBusy 24%). Each half reads disjoint channels.
__global__ __launch_bounds__(128) void k_conv_off(const float* __restrict__ f,
                                                  const float* __restrict__ wP,
                                                  float* __restrict__ off_half) {
    int t   = threadIdx.x;          // 0..127 = h
    int bid = blockIdx.x;
    int b   = bid & 7;              // XCD swizzle: each XCD owns one batch
    int w   = (bid >> 3) & 127;     // wave-uniform
    int ch  = bid >> 10;            // c-half 0/1 (wave-uniform)
    int h   = t;

    float em = (h == 0)   ? 0.f : 1.f;   // zero the dh=-1 tap at image edge
    float ep = (h == 127) ? 0.f : 1.f;   // zero the dh=+1 tap at image edge
    int   om = h + ((h == 0)   ? 0 : -1);
    int   op = h + ((h == 127) ? 0 : 1);

    const float* fb = f + (size_t)b*1048576 + (size_t)(ch*32)*16384 + (size_t)w*128;
    const float* wb = wP + ch*32*81;

    float acc[9];
#pragma unroll
    for (int ck = 0; ck < 9; ck++) acc[ck] = 0.f;

#pragma unroll 4
    for (int c = 0; c < 32; c++) {
        const float* p  = fb + c*16384;
        const float* wc = wb + c*81;
#pragma unroll
        for (int dw = -1; dw <= 1; dw++) {
            int wy = w + dw;
            if ((unsigned)wy < 128u) {           // uniform branch
                const float* q = p + dw*128;
                float v0 = q[om] * em;
                float v1 = q[h];
                float v2 = q[op] * ep;
                const float* ww = wc + (dw+1)*27;
#pragma unroll
                for (int ck = 0; ck < 9; ck++)
                    acc[ck] += v0*ww[ck*3] + v1*ww[ck*3+1] + v2*ww[ck*3+2];
            }
        }
    }

    float* dst = off_half + (size_t)ch*1179648;
    int pixoff = (w << 7) + h;
#pragma unroll
    for (int ck = 0; ck < 9; ck++)
        dst[((b*9 + ck) << 14) + pixoff] = acc[ck];
}

// ---------------- sum halves -> off_pre, BN stats ----------------
__global__ __launch_bounds__(256) void k_bn_stats(const float* __restrict__ off_half,
                                                  float* __restrict__ off_pre,
                                                  float* __restrict__ bnstats) {
    __shared__ float wred[4][2];
    int bid = blockIdx.x;           // 288 = b*36 + ck*4 + wq
    int b  = bid / 36;
    int rem = bid % 36;
    int ck = rem / 4;
    int wq = rem % 4;
    int t  = threadIdx.x;
    int base4 = (((b*9+ck) << 14) + wq*4096) >> 2;

    const float4* h0 = (const float4*)off_half;
    const float4* h1 = (const float4*)(off_half + 1179648);
    float4* op = (float4*)off_pre;

    float s = 0.f, q = 0.f;
#pragma unroll
    for (int i = 0; i < 4; i++) {
        int idx = base4 + t + i*256;
        float4 a = h0[idx], bb = h1[idx];
        float4 v;
        v.x = a.x + bb.x; v.y = a.y + bb.y; v.z = a.z + bb.z; v.w = a.w + bb.w;
        op[idx] = v;
        s += v.x + v.y + v.z + v.w;
        q += v.x*v.x + v.y*v.y + v.z*v.z + v.w*v.w;
    }
    for (int off = 32; off; off >>= 1) {
        s += __shfl_down(s, off);
        q += __shfl_down(q, off);
    }
    if ((t & 63) == 0) { wred[t >> 6][0] = s; wred[t >> 6][1] = q; }
    __syncthreads();
    if (t == 0) atomicAdd(&bnstats[ck*2],   wred[0][0]+wred[1][0]+wred[2][0]+wred[3][0]);
    if (t == 1) atomicAdd(&bnstats[ck*2+1], wred[0][1]+wred[1][1]+wred[2][1]+wred[3][1]);
}

// ---------------- BN finalize ----------------
__global__ void k_bn_fin(const float* __restrict__ bnstats,
                         const float* __restrict__ bn_gamma,
                         const float* __restrict__ bn_beta,
                         float* __restrict__ bnAB) {
    int t = threadIdx.x;
    if (t < 9) {
        float n    = (float)NPIX;
        float mean = bnstats[t*2] / n;
        float var  = bnstats[t*2+1] / n - mean*mean;
        float A    = bn_gamma[t] / sqrtf(var + EPS_);
        bnAB[t*2]   = A;
        bnAB[t*2+1] = bn_beta[t] - mean * A;
    }
}

// ---------------- fused: offsets, 2-tap y-lerp sample (bf16), MFMA strip conv, GN stats ----------------
__global__ __launch_bounds__(256) void k_sample_dsc(const unsigned short* __restrict__ featbf,
                                                    const float* __restrict__ off_pre,
                                                    const float* __restrict__ bnAB,
                                                    const unsigned short* __restrict__ wTbf,
                                                    const float* __restrict__ b_dsc,
                                                    float* __restrict__ xpre,
                                                    float* __restrict__ gstats) {
    __shared__ __align__(16) unsigned char lds_samp[128*128]; // [h][c] bf16, XOR-swizzled rows
    __shared__ __align__(16) unsigned char lds_wk[64*128];    // [o][c] bf16, XOR-swizzled rows
    __shared__ float ynew[9][128];
    __shared__ float red[16][2];

    int t = threadIdx.x;
    // XCD swizzle: 1024 blocks = 8 XCD x 128; each XCD owns one b
    int b = blockIdx.x & 7, w = blockIdx.x >> 3;

    if (t < 128) {
        int h = t;
        float y[9];
#pragma unroll
        for (int ck = 0; ck < 9; ck++) {
            float v = off_pre[((b*9+ck) << 14) + (w << 7) + h];
            y[ck] = tanhf(bnAB[ck*2]*v + bnAB[ck*2+1]);
        }
        float ofn[9];
        ofn[4] = 0.f;
        ofn[5] = y[5]; ofn[6] = y[5]+y[6]; ofn[7] = y[5]+y[6]+y[7];
        ofn[3] = y[3]; ofn[2] = y[3]+y[2]; ofn[1] = y[3]+y[2]+y[1];
        ofn[0] = y[0]; ofn[8] = y[8];
#pragma unroll
        for (int k = 0; k < 9; k++) ynew[k][h] = (float)w + ofn[k];
    }
    if (t < 16) { red[t][0] = 0.f; red[t][1] = 0.f; }

    f32x4 acc[2][4];
#pragma unroll
    for (int mi = 0; mi < 2; mi++)
#pragma unroll
        for (int ni = 0; ni < 4; ni++) {
            acc[mi][ni][0] = 0.f; acc[mi][ni][1] = 0.f;
            acc[mi][ni][2] = 0.f; acc[mi][ni][3] = 0.f;
        }

    int lane = t & 63, wv = t >> 6;
    int m0 = wv * 32;                 // wave's 32-row M tile
    int lm = lane & 15, lk = lane >> 4;
    int hs = t >> 1;                  // sampling row
    int cq = (t & 1) * 4;             // uint4 offset (32 ch half)

    __syncthreads();

    for (int k = 0; k < 9; k++) {
        if (k) __syncthreads();       // previous iter's MFMA reads done

        // ---- stage weight k-slice [64 o][64 c] bf16 into swizzled LDS ----
        {
            const uint4* src = (const uint4*)(wTbf + (k << 12));
#pragma unroll
            for (int i = 0; i < 2; i++) {
                int ci = t + i*256;                 // 0..511 16B chunks
                uint4 v = src[ci];
                int o  = ci >> 3;
                int cb = (ci & 7) << 4;
                *(uint4*)(lds_wk + o*128 + (cb ^ ((o & 7) << 4))) = v;
            }
        }

        // ---- 2-tap y-lerp sample, row hs, 32 ch -> bf16 LDS ----
        // x_s is integer -> x-weights are {1,0} in-bounds, exact 0 outside
        {
            int x0 = k - 4 + hs;
            unsigned char* dst = lds_samp + hs*128;
            int bcol0 = (t & 1) * 64;
            if ((unsigned)x0 < 127u) {
                float ys = ynew[k][hs];
                int y0  = (int)floorf(ys);
                int y0c = min(max(y0, 0), 127), y1c = min(max(y0+1, 0), 127);
                float wa = (float)y1c - ys;     // top tap weight
                float wc = ys - (float)y0c;     // bottom tap weight
                const unsigned short* pb = featbf + ((size_t)b << 20);
                const uint4* p0 = (const uint4*)(pb + (y0c*128 + x0)*64) + cq;
                const uint4* p1 = (const uint4*)(pb + (y1c*128 + x0)*64) + cq;
#pragma unroll
                for (int ci = 0; ci < 4; ci++) {
                    uint4 a = p0[ci], c = p1[ci];
                    uint4 u;
                    u.x = pack2bf(bflo(a.x)*wa + bflo(c.x)*wc, bfhi(a.x)*wa + bfhi(c.x)*wc);
                    u.y = pack2bf(bflo(a.y)*wa + bflo(c.y)*wc, bfhi(a.y)*wa + bfhi(c.y)*wc);
                    u.z = pack2bf(bflo(a.z)*wa + bflo(c.z)*wc, bfhi(a.z)*wa + bfhi(c.z)*wc);
                    u.w = pack2bf(bflo(a.w)*wa + bflo(c.w)*wc, bfhi(a.w)*wa + bfhi(c.w)*wc);
                    *(uint4*)(dst + ((bcol0 + ci*16) ^ ((hs & 7) << 4))) = u;
                }
            } else {
                uint4 z = make_uint4(0,0,0,0);
#pragma unroll
                for (int ci = 0; ci < 4; ci++)
                    *(uint4*)(dst + ((bcol0 + ci*16) ^ ((hs & 7) << 4))) = z;
            }
        }
        __syncthreads();

        // ---- MFMA: acc[mi][ni] += A[32k-slice] * B ----
#pragma unroll
        for (int ks = 0; ks < 2; ks++) {
            bf16x8 af[2], bfr[4];
#pragma unroll
            for (int mi = 0; mi < 2; mi++) {
                int h = m0 + mi*16 + lm;
                af[mi] = *(const bf16x8*)(lds_samp + h*128 + ((ks*64 + lk*16) ^ ((h & 7) << 4)));
            }
#pragma unroll
            for (int ni = 0; ni < 4; ni++) {
                int o = ni*16 + lm;
                bfr[ni] = *(const bf16x8*)(lds_wk + o*128 + ((ks*64 + lk*16) ^ ((o & 7) << 4)));
            }
#pragma unroll
            for (int mi = 0; mi < 2; mi++)
#pragma unroll
                for (int ni = 0; ni < 4; ni++)
                    acc[mi][ni] = __builtin_amdgcn_mfma_f32_16x16x32_bf16(af[mi], bfr[ni], acc[mi][ni], 0, 0, 0);
        }
    }

    // ---- epilogue: bias, xpre write (C/D: row=lk*4+reg, col=lm), GN partial stats ----
#pragma unroll
    for (int ni = 0; ni < 4; ni++) {
        int o = ni*16 + lm;
        float bias = b_dsc[o];
        float s1 = 0.f, s2 = 0.f;
#pragma unroll
        for (int mi = 0; mi < 2; mi++) {
            float4 r;
            r.x = acc[mi][ni][0] + bias;
            r.y = acc[mi][ni][1] + bias;
            r.z = acc[mi][ni][2] + bias;
            r.w = acc[mi][ni][3] + bias;
            s1 += r.x + r.y + r.z + r.w;
            s2 += r.x*r.x + r.y*r.y + r.z*r.z + r.w*r.w;
            int h = m0 + mi*16 + lk*4;
            *(float4*)(xpre + (((b*64 + o) << 14) + (w << 7) + h)) = r;
        }
        s1 += __shfl_xor(s1, 1);  s1 += __shfl_xor(s1, 2);
        s1 += __shfl_xor(s1, 16); s1 += __shfl_xor(s1, 32);
        s2 += __shfl_xor(s2, 1);  s2 += __shfl_xor(s2, 2);
        s2 += __shfl_xor(s2, 16); s2 += __shfl_xor(s2, 32);
        if (lk == 0 && (lm & 3) == 0) {
            atomicAdd(&red[ni*4 + (lm >> 2)][0], s1);
            atomicAdd(&red[ni*4 + (lm >> 2)][1], s2);
        }
    }
    __syncthreads();
    if (t < 16) {
        atomicAdd(&gstats[(b*16 + t)*2],   red[t][0]);
        atomicAdd(&gstats[(b*16 + t)*2+1], red[t][1]);
    }
}

// ---------------- GN finalize ----------------
__global__ void k_gn_fin(const float* __restrict__ gstats, float* __restrict__ gnfin) {
    int t = threadIdx.x;
    if (t < 128) {
        float n    = 65536.f;           // 4 ch * 128 * 128
        float mean = gstats[t*2] / n;
        float var  = gstats[t*2+1] / n - mean*mean;
        gnfin[t*2]   = mean;
        gnfin[t*2+1] = 1.0f / sqrtf(var + EPS_);
    }
}

// ---------------- GN apply + ReLU ----------------
__global__ __launch_bounds__(256) void k_gn_apply(const float* __restrict__ xpre,
                                                  const float* __restrict__ gnfin,
                                                  const float* __restrict__ gn_gamma,
                                                  const float* __restrict__ gn_beta,
                                                  float* __restrict__ out) {
    int i4  = blockIdx.x*256 + threadIdx.x;
    int idx = i4 * 4;
    int o = (idx >> 14) & 63;
    int b = idx >> 20;
    int g = o >> 2;
    float mean = gnfin[(b*16+g)*2];
    float istd = gnfin[(b*16+g)*2+1];
    float ga = gn_gamma[o] * istd;
    float be = gn_beta[o] - mean * ga;
    float4 v = *(const float4*)(xpre + idx);
    v.x = fmaxf(v.x*ga + be, 0.f);
    v.y = fmaxf(v.y*ga + be, 0.f);
    v.z = fmaxf(v.z*ga + be, 0.f);
    v.w = fmaxf(v.w*ga + be, 0.f);
    *(float4*)(out + idx) = v;
}

extern "C" void kernel_launch(void* const* d_in, const int* in_sizes, int n_in,
                              void* d_out, int out_size, void* d_ws, size_t ws_size,
                              hipStream_t stream) {
    const float* f        = (const float*)d_in[0];
    const float* w_off    = (const float*)d_in[1];
    const float* bn_gamma = (const float*)d_in[3];
    const float* bn_beta  = (const float*)d_in[4];
    const float* w_dsc    = (const float*)d_in[5];
    const float* b_dsc    = (const float*)d_in[6];
    const float* gn_gamma = (const float*)d_in[7];
    const float* gn_beta  = (const float*)d_in[8];

    float* ws      = (float*)d_ws;
    unsigned short* featbf = (unsigned short*)(ws + FEATBF_OFF);
    float* xpre    = ws + XPRE_OFF;
    float* off_pre = ws + OFFPRE_OFF;
    float* off_half= ws + OFFH_OFF;
    unsigned short* wTbf = (unsigned short*)(ws + WT_OFF);
    float* wP      = ws + WP_OFF;
    float* bnstats = ws + BNSTATS_OFF;
    float* bnAB    = ws + BNAB_OFF;
    float* gstats  = ws + GSTATS_OFF;
    float* gnfin   = ws + GNFIN_OFF;

    hipMemsetAsync(bnstats, 0, STATS_BYTES, stream);

    k_nhwc<<<2048, 256, 0, stream>>>(f, featbf);
    k_wt<<<144, 256, 0, stream>>>(w_dsc, wTbf);
    k_wp<<<21, 256, 0, stream>>>(w_off, wP);
    k_conv_off<<<2048, 128, 0, stream>>>(f, wP, off_half);
    k_bn_stats<<<288, 256, 0, stream>>>(off_half, off_pre, bnstats);
    k_bn_fin<<<1, 32, 0, stream>>>(bnstats, bn_gamma, bn_beta, bnAB);
    k_sample_dsc<<<1024, 256, 0, stream>>>(featbf, off_pre, bnAB, wTbf, b_dsc, xpre, gstats);
    k_gn_fin<<<1, 128, 0, stream>>>(gstats, gnfin);
    k_gn_apply<<<8192, 256, 0, stream>>>(xpre, gnfin, gn_gamma, gn_beta, (float*)d_out);
}

// Round 13
// 123.012 us; speedup vs baseline: 5.8778x; 1.0092x over previous
//
#include <hip/hip_runtime.h>

#define B_   8
#define C_   64
#define W_   128
#define H_   128
#define K_   9
#define OUT_ 64
#define NPIX (B_*W_*H_)      // 131072
#define EPS_ 1e-5f

typedef __attribute__((ext_vector_type(8))) short bf16x8;
typedef __attribute__((ext_vector_type(4))) float f32x4;

// ---------------- workspace layout (float offsets) ----------------
#define FEATBF_OFF  0                      // B*W*H*C bf16 (4194304 f)
#define XPRE_OFF    4194304                // B*64*W*H bf16 (4194304 f)
#define OFFPRE_OFF  8388608                // B*9*W*H = 1179648
#define OFFH_OFF    9568256                // 4*B*9*W*H = 4718592 (c-split partials)
#define WT_OFF      14286848               // 9*64*64 bf16 (18432 f)
#define WP_OFF      14305280               // 64*81 = 5184
#define BNSTATS_OFF 14310464               // 18
#define BNAB_OFF    14310482               // 18
#define GSTATS_OFF  14310500               // 256
#define GNFIN_OFF   14310756               // 256
#define STATS_BYTES ((18+18+256+256)*sizeof(float))

__device__ __forceinline__ unsigned pack2bf(float a, float b) {
    union { float f; unsigned u; } ua, ub;
    ua.f = a; ub.f = b;
    unsigned x = ua.u, y = ub.u;
    x += 0x7fffu + ((x >> 16) & 1u);       // RNE to bf16
    y += 0x7fffu + ((y >> 16) & 1u);
    return (x >> 16) | (y & 0xffff0000u);
}
__device__ __forceinline__ float bflo(unsigned u) {
    union { unsigned u; float f; } v; v.u = u << 16; return v.f;
}
__device__ __forceinline__ float bfhi(unsigned u) {
    union { unsigned u; float f; } v; v.u = u & 0xffff0000u; return v.f;
}

// ---------------- NCHW -> NHWC bf16 transpose of f (sampling path only) ----------------
__global__ __launch_bounds__(256) void k_nhwc(const float* __restrict__ f,
                                              unsigned short* __restrict__ featbf) {
    __shared__ float tile[64][65];
    int bid = blockIdx.x;
    int ht = bid & 1;            // 64-high h tile
    int w  = (bid >> 1) & 127;
    int b  = bid >> 8;
    int t  = threadIdx.x;
    int lh = t & 63;
    int c0 = (t >> 6) * 16;
    const float* fp = f + (((b*64)*128 + w)*128) + ht*64 + lh;
#pragma unroll
    for (int i = 0; i < 16; i++) {
        int c = c0 + i;
        tile[c][lh] = fp[c*16384];
    }
    __syncthreads();
    int lc = t & 63;
    int h0 = (t >> 6) * 16;
    unsigned short* obf = featbf + ((size_t)((b*128 + w)*128) + ht*64)*64 + lc;
#pragma unroll
    for (int i = 0; i < 16; i++) {
        int hr = h0 + i;
        union { float f; unsigned u; } v; v.f = tile[lc][hr];
        unsigned x = v.u + 0x7fffu + ((v.u >> 16) & 1u);
        obf[(size_t)hr*64] = (unsigned short)(x >> 16);
    }
}

// ---------------- w_dsc (O,C,K) -> wTbf[k][o][c] bf16 ----------------
__global__ void k_wt(const float* __restrict__ w_dsc, unsigned short* __restrict__ wTbf) {
    int i = blockIdx.x*256 + threadIdx.x;       // < 36864
    if (i >= 9*64*64) return;
    int c = i & 63;
    int o = (i >> 6) & 63;
    int k = i >> 12;
    union { float f; unsigned u; } v;
    v.f = w_dsc[(o*64 + c)*9 + k];
    unsigned x = v.u + 0x7fffu + ((v.u >> 16) & 1u);
    wTbf[i] = (unsigned short)(x >> 16);
}

// ---------------- w_off (18,64,3,3) -> wP[c][dw][ck][dh] ----------------
__global__ void k_wp(const float* __restrict__ w_off, float* __restrict__ wP) {
    int i = blockIdx.x*256 + threadIdx.x;       // < 5184
    if (i >= 64*81) return;
    int c    = i / 81;
    int rem  = i % 81;
    int dw   = rem / 27;
    int rem2 = rem % 27;
    int ck   = rem2 / 3;
    int dh   = rem2 % 3;
    wP[i] = w_off[ck*576 + c*9 + dw*3 + dh];
}

// ---------------- 3x3 conv, c-split x4, shuffle taps (NCHW f, lane = h) ----------------
// fp32 path REQUIRED (offset feeds a discontinuous sampler; see R7 failure).
// b_off dropped: per-channel constant cancels exactly through BN.
// v0/v2 taps come from neighbor lanes via shfl (kills 6 of 9 loads/c and all
// unaligned 2-line transactions); only the h=63/64 cross-wave seam loads.
__global__ __launch_bounds__(128) void k_conv_off(const float* __restrict__ f,
                                                  const float* __restrict__ wP,
                                                  float* __restrict__ off_half) {
    int t   = threadIdx.x;          // 0..127 = h
    int bid = blockIdx.x;
    int b   = bid & 7;              // XCD swizzle: each XCD owns one batch
    int w   = (bid >> 3) & 127;     // wave-uniform
    int cq  = bid >> 10;            // c-quarter 0..3 (wave-uniform)
    int h   = t;

    float em = (h == 0)   ? 0.f : 1.f;
    float ep = (h == 127) ? 0.f : 1.f;

    const float* fb = f + (size_t)b*1048576 + (size_t)(cq*16)*16384 + (size_t)w*128;
    const float* wb = wP + cq*16*81;

    float acc[9];
#pragma unroll
    for (int ck = 0; ck < 9; ck++) acc[ck] = 0.f;

#pragma unroll 4
    for (int c = 0; c < 16; c++) {
        const float* p  = fb + c*16384;
        const float* wc = wb + c*81;
#pragma unroll
        for (int dw = -1; dw <= 1; dw++) {
            int wy = w + dw;
            if ((unsigned)wy < 128u) {           // uniform branch
                const float* q = p + dw*128;
                float v1 = q[h];
                float v0 = __shfl_up(v1, 1);
                float v2 = __shfl_down(v1, 1);
                if (t == 64) v0 = q[63];         // cross-wave seam
                if (t == 63) v2 = q[64];
                v0 *= em; v2 *= ep;
                const float* ww = wc + (dw+1)*27;
#pragma unroll
                for (int ck = 0; ck < 9; ck++)
                    acc[ck] += v0*ww[ck*3] + v1*ww[ck*3+1] + v2*ww[ck*3+2];
            }
        }
    }

    float* dst = off_half + (size_t)cq*1179648;
    int pixoff = (w << 7) + h;
#pragma unroll
    for (int ck = 0; ck < 9; ck++)
        dst[((b*9 + ck) << 14) + pixoff] = acc[ck];
}

// ---------------- sum quarters -> off_pre, BN stats ----------------
__global__ __launch_bounds__(256) void k_bn_stats(const float* __restrict__ off_half,
                                                  float* __restrict__ off_pre,
                                                  float* __restrict__ bnstats) {
    __shared__ float wred[4][2];
    int bid = blockIdx.x;           // 288 = b*36 + ck*4 + wq
    int b  = bid / 36;
    int rem = bid % 36;
    int ck = rem / 4;
    int wq = rem % 4;
    int t  = threadIdx.x;
    int base4 = (((b*9+ck) << 14) + wq*4096) >> 2;

    const float4* h0 = (const float4*)off_half;
    const float4* h1 = (const float4*)(off_half + 1179648);
    const float4* h2 = (const float4*)(off_half + 2359296);
    const float4* h3 = (const float4*)(off_half + 3538944);
    float4* op = (float4*)off_pre;

    float s = 0.f, q = 0.f;
#pragma unroll
    for (int i = 0; i < 4; i++) {
        int idx = base4 + t + i*256;
        float4 a = h0[idx], bb = h1[idx], cc = h2[idx], dd = h3[idx];
        float4 v;
        v.x = (a.x + bb.x) + (cc.x + dd.x);
        v.y = (a.y + bb.y) + (cc.y + dd.y);
        v.z = (a.z + bb.z) + (cc.z + dd.z);
        v.w = (a.w + bb.w) + (cc.w + dd.w);
        op[idx] = v;
        s += v.x + v.y + v.z + v.w;
        q += v.x*v.x + v.y*v.y + v.z*v.z + v.w*v.w;
    }
    for (int off = 32; off; off >>= 1) {
        s += __shfl_down(s, off);
        q += __shfl_down(q, off);
    }
    if ((t & 63) == 0) { wred[t >> 6][0] = s; wred[t >> 6][1] = q; }
    __syncthreads();
    if (t == 0) atomicAdd(&bnstats[ck*2],   wred[0][0]+wred[1][0]+wred[2][0]+wred[3][0]);
    if (t == 1) atomicAdd(&bnstats[ck*2+1], wred[0][1]+wred[1][1]+wred[2][1]+wred[3][1]);
}

// ---------------- BN finalize ----------------
__global__ void k_bn_fin(const float* __restrict__ bnstats,
                         const float* __restrict__ bn_gamma,
                         const float* __restrict__ bn_beta,
                         float* __restrict__ bnAB) {
    int t = threadIdx.x;
    if (t < 9) {
        float n    = (float)NPIX;
        float mean = bnstats[t*2] / n;
        float var  = bnstats[t*2+1] / n - mean*mean;
        float A    = bn_gamma[t] / sqrtf(var + EPS_);
        bnAB[t*2]   = A;
        bnAB[t*2+1] = bn_beta[t] - mean * A;
    }
}

// ---------------- fused: offsets, 2-tap y-lerp sample (bf16), MFMA strip conv, GN stats ----------------
__global__ __launch_bounds__(256) void k_sample_dsc(const unsigned short* __restrict__ featbf,
                                                    const float* __restrict__ off_pre,
                                                    const float* __restrict__ bnAB,
                                                    const unsigned short* __restrict__ wTbf,
                                                    const float* __restrict__ b_dsc,
                                                    unsigned short* __restrict__ xprebf,
                                                    float* __restrict__ gstats) {
    __shared__ __align__(16) unsigned char lds_samp[128*128]; // [h][c] bf16, XOR-swizzled rows
    __shared__ __align__(16) unsigned char lds_wk[64*128];    // [o][c] bf16, XOR-swizzled rows
    __shared__ float ynew[9][128];
    __shared__ float red[16][2];

    int t = threadIdx.x;
    // XCD swizzle: 1024 blocks = 8 XCD x 128; each XCD owns one b
    int b = blockIdx.x & 7, w = blockIdx.x >> 3;

    if (t < 128) {
        int h = t;
        float y[9];
#pragma unroll
        for (int ck = 0; ck < 9; ck++) {
            float v = off_pre[((b*9+ck) << 14) + (w << 7) + h];
            y[ck] = tanhf(bnAB[ck*2]*v + bnAB[ck*2+1]);
        }
        float ofn[9];
        ofn[4] = 0.f;
        ofn[5] = y[5]; ofn[6] = y[5]+y[6]; ofn[7] = y[5]+y[6]+y[7];
        ofn[3] = y[3]; ofn[2] = y[3]+y[2]; ofn[1] = y[3]+y[2]+y[1];
        ofn[0] = y[0]; ofn[8] = y[8];
#pragma unroll
        for (int k = 0; k < 9; k++) ynew[k][h] = (float)w + ofn[k];
    }
    if (t < 16) { red[t][0] = 0.f; red[t][1] = 0.f; }

    f32x4 acc[2][4];
#pragma unroll
    for (int mi = 0; mi < 2; mi++)
#pragma unroll
        for (int ni = 0; ni < 4; ni++) {
            acc[mi][ni][0] = 0.f; acc[mi][ni][1] = 0.f;
            acc[mi][ni][2] = 0.f; acc[mi][ni][3] = 0.f;
        }

    int lane = t & 63, wv = t >> 6;
    int m0 = wv * 32;                 // wave's 32-row M tile
    int lm = lane & 15, lk = lane >> 4;
    int hs = t >> 1;                  // sampling row
    int cq = (t & 1) * 4;             // uint4 offset (32 ch half)

    __syncthreads();

    for (int k = 0; k < 9; k++) {
        if (k) __syncthreads();       // previous iter's MFMA reads done

        // ---- stage weight k-slice [64 o][64 c] bf16 into swizzled LDS ----
        {
            const uint4* src = (const uint4*)(wTbf + (k << 12));
#pragma unroll
            for (int i = 0; i < 2; i++) {
                int ci = t + i*256;                 // 0..511 16B chunks
                uint4 v = src[ci];
                int o  = ci >> 3;
                int cb = (ci & 7) << 4;
                *(uint4*)(lds_wk + o*128 + (cb ^ ((o & 7) << 4))) = v;
            }
        }

        // ---- 2-tap y-lerp sample, row hs, 32 ch -> bf16 LDS ----
        // x_s is integer -> x-weights are {1,0} in-bounds, exact 0 outside
        {
            int x0 = k - 4 + hs;
            unsigned char* dst = lds_samp + hs*128;
            int bcol0 = (t & 1) * 64;
            if ((unsigned)x0 < 127u) {
                float ys = ynew[k][hs];
                int y0  = (int)floorf(ys);
                int y0c = min(max(y0, 0), 127), y1c = min(max(y0+1, 0), 127);
                float wa = (float)y1c - ys;     // top tap weight
                float wc = ys - (float)y0c;     // bottom tap weight
                const unsigned short* pb = featbf + ((size_t)b << 20);
                const uint4* p0 = (const uint4*)(pb + (y0c*128 + x0)*64) + cq;
                const uint4* p1 = (const uint4*)(pb + (y1c*128 + x0)*64) + cq;
#pragma unroll
                for (int ci = 0; ci < 4; ci++) {
                    uint4 a = p0[ci], c = p1[ci];
                    uint4 u;
                    u.x = pack2bf(bflo(a.x)*wa + bflo(c.x)*wc, bfhi(a.x)*wa + bfhi(c.x)*wc);
                    u.y = pack2bf(bflo(a.y)*wa + bflo(c.y)*wc, bfhi(a.y)*wa + bfhi(c.y)*wc);
                    u.z = pack2bf(bflo(a.z)*wa + bflo(c.z)*wc, bfhi(a.z)*wa + bfhi(c.z)*wc);
                    u.w = pack2bf(bflo(a.w)*wa + bflo(c.w)*wc, bfhi(a.w)*wa + bfhi(c.w)*wc);
                    *(uint4*)(dst + ((bcol0 + ci*16) ^ ((hs & 7) << 4))) = u;
                }
            } else {
                uint4 z = make_uint4(0,0,0,0);
#pragma unroll
                for (int ci = 0; ci < 4; ci++)
                    *(uint4*)(dst + ((bcol0 + ci*16) ^ ((hs & 7) << 4))) = z;
            }
        }
        __syncthreads();

        // ---- MFMA: acc[mi][ni] += A[32k-slice] * B ----
#pragma unroll
        for (int ks = 0; ks < 2; ks++) {
            bf16x8 af[2], bfr[4];
#pragma unroll
            for (int mi = 0; mi < 2; mi++) {
                int h = m0 + mi*16 + lm;
                af[mi] = *(const bf16x8*)(lds_samp + h*128 + ((ks*64 + lk*16) ^ ((h & 7) << 4)));
            }
#pragma unroll
            for (int ni = 0; ni < 4; ni++) {
                int o = ni*16 + lm;
                bfr[ni] = *(const bf16x8*)(lds_wk + o*128 + ((ks*64 + lk*16) ^ ((o & 7) << 4)));
            }
#pragma unroll
            for (int mi = 0; mi < 2; mi++)
#pragma unroll
                for (int ni = 0; ni < 4; ni++)
                    acc[mi][ni] = __builtin_amdgcn_mfma_f32_16x16x32_bf16(af[mi], bfr[ni], acc[mi][ni], 0, 0, 0);
        }
    }

    // ---- epilogue: bias, bf16 xpre write (C/D: row=lk*4+reg, col=lm), GN stats ----
#pragma unroll
    for (int ni = 0; ni < 4; ni++) {
        int o = ni*16 + lm;
        float bias = b_dsc[o];
        float s1 = 0.f, s2 = 0.f;
#pragma unroll
        for (int mi = 0; mi < 2; mi++) {
            float4 r;
            r.x = acc[mi][ni][0] + bias;
            r.y = acc[mi][ni][1] + bias;
            r.z = acc[mi][ni][2] + bias;
            r.w = acc[mi][ni][3] + bias;
            s1 += r.x + r.y + r.z + r.w;
            s2 += r.x*r.x + r.y*r.y + r.z*r.z + r.w*r.w;
            int h = m0 + mi*16 + lk*4;
            uint2 u2;
            u2.x = pack2bf(r.x, r.y);
            u2.y = pack2bf(r.z, r.w);
            *(uint2*)(xprebf + (((b*64 + o) << 14) + (w << 7) + h)) = u2;
        }
        s1 += __shfl_xor(s1, 1);  s1 += __shfl_xor(s1, 2);
        s1 += __shfl_xor(s1, 16); s1 += __shfl_xor(s1, 32);
        s2 += __shfl_xor(s2, 1);  s2 += __shfl_xor(s2, 2);
        s2 += __shfl_xor(s2, 16); s2 += __shfl_xor(s2, 32);
        if (lk == 0 && (lm & 3) == 0) {
            atomicAdd(&red[ni*4 + (lm >> 2)][0], s1);
            atomicAdd(&red[ni*4 + (lm >> 2)][1], s2);
        }
    }
    __syncthreads();
    if (t < 16) {
        atomicAdd(&gstats[(b*16 + t)*2],   red[t][0]);
        atomicAdd(&gstats[(b*16 + t)*2+1], red[t][1]);
    }
}

// ---------------- GN finalize ----------------
__global__ void k_gn_fin(const float* __restrict__ gstats, float* __restrict__ gnfin) {
    int t = threadIdx.x;
    if (t < 128) {
        float n    = 65536.f;           // 4 ch * 128 * 128
        float mean = gstats[t*2] / n;
        float var  = gstats[t*2+1] / n - mean*mean;
        gnfin[t*2]   = mean;
        gnfin[t*2+1] = 1.0f / sqrtf(var + EPS_);
    }
}

// ---------------- GN apply + ReLU (bf16 in, fp32 out) ----------------
__global__ __launch_bounds__(256) void k_gn_apply(const unsigned short* __restrict__ xprebf,
                                                  const float* __restrict__ gnfin,
                                                  const float* __restrict__ gn_gamma,
                                                  const float* __restrict__ gn_beta,
                                                  float* __restrict__ out) {
    int i8  = blockIdx.x*256 + threadIdx.x;
    int idx = i8 * 8;
    int o = (idx >> 14) & 63;
    int b = idx >> 20;
    int g = o >> 2;
    float mean = gnfin[(b*16+g)*2];
    float istd = gnfin[(b*16+g)*2+1];
    float ga = gn_gamma[o] * istd;
    float be = gn_beta[o] - mean * ga;
    uint4 v = *(const uint4*)(xprebf + idx);
    float4 r0, r1;
    r0.x = fmaxf(bflo(v.x)*ga + be, 0.f);
    r0.y = fmaxf(bfhi(v.x)*ga + be, 0.f);
    r0.z = fmaxf(bflo(v.y)*ga + be, 0.f);
    r0.w = fmaxf(bfhi(v.y)*ga + be, 0.f);
    r1.x = fmaxf(bflo(v.z)*ga + be, 0.f);
    r1.y = fmaxf(bfhi(v.z)*ga + be, 0.f);
    r1.z = fmaxf(bflo(v.w)*ga + be, 0.f);
    r1.w = fmaxf(bfhi(v.w)*ga + be, 0.f);
    *(float4*)(out + idx)     = r0;
    *(float4*)(out + idx + 4) = r1;
}

extern "C" void kernel_launch(void* const* d_in, const int* in_sizes, int n_in,
                              void* d_out, int out_size, void* d_ws, size_t ws_size,
                              hipStream_t stream) {
    const float* f        = (const float*)d_in[0];
    const float* w_off    = (const float*)d_in[1];
    const float* bn_gamma = (const float*)d_in[3];
    const float* bn_beta  = (const float*)d_in[4];
    const float* w_dsc    = (const float*)d_in[5];
    const float* b_dsc    = (const float*)d_in[6];
    const float* gn_gamma = (const float*)d_in[7];
    const float* gn_beta  = (const float*)d_in[8];

    float* ws      = (float*)d_ws;
    unsigned short* featbf = (unsigned short*)(ws + FEATBF_OFF);
    unsigned short* xprebf = (unsigned short*)(ws + XPRE_OFF);
    float* off_pre = ws + OFFPRE_OFF;
    float* off_half= ws + OFFH_OFF;
    unsigned short* wTbf = (unsigned short*)(ws + WT_OFF);
    float* wP      = ws + WP_OFF;
    float* bnstats = ws + BNSTATS_OFF;
    float* bnAB    = ws + BNAB_OFF;
    float* gstats  = ws + GSTATS_OFF;
    float* gnfin   = ws + GNFIN_OFF;

    hipMemsetAsync(bnstats, 0, STATS_BYTES, stream);

    k_nhwc<<<2048, 256, 0, stream>>>(f, featbf);
    k_wt<<<144, 256, 0, stream>>>(w_dsc, wTbf);
    k_wp<<<21, 256, 0, stream>>>(w_off, wP);
    k_conv_off<<<4096, 128, 0, stream>>>(f, wP, off_half);
    k_bn_stats<<<288, 256, 0, stream>>>(off_half, off_pre, bnstats);
    k_bn_fin<<<1, 32, 0, stream>>>(bnstats, bn_gamma, bn_beta, bnAB);
    k_sample_dsc<<<1024, 256, 0, stream>>>(featbf, off_pre, bnAB, wTbf, b_dsc, xprebf, gstats);
    k_gn_fin<<<1, 128, 0, stream>>>(gstats, gnfin);
    k_gn_apply<<<4096, 256, 0, stream>>>(xprebf, gnfin, gn_gamma, gn_beta, (float*)d_out);
}